// Round 1
// baseline (6972.466 us; speedup 1.0000x reference)
//
#include <hip/hip_runtime.h>
#include <hip/hip_bf16.h>
#include <math.h>

// METG forward, f32 baseline.
// Shapes: B=32 S=512 F_IN=64 D=512 DFF=2048 MEM=1024 L=3 H=8 DH=64

namespace {

constexpr int Mrows = 32 * 512;  // 16384

#define OUTER16(ACC, A4, B4) do { \
  ACC[0][0] += (A4).x*(B4).x; ACC[0][1] += (A4).x*(B4).y; ACC[0][2] += (A4).x*(B4).z; ACC[0][3] += (A4).x*(B4).w; \
  ACC[1][0] += (A4).y*(B4).x; ACC[1][1] += (A4).y*(B4).y; ACC[1][2] += (A4).y*(B4).z; ACC[1][3] += (A4).y*(B4).w; \
  ACC[2][0] += (A4).z*(B4).x; ACC[2][1] += (A4).z*(B4).y; ACC[2][2] += (A4).z*(B4).z; ACC[2][3] += (A4).z*(B4).w; \
  ACC[3][0] += (A4).w*(B4).x; ACC[3][1] += (A4).w*(B4).y; ACC[3][2] += (A4).w*(B4).z; ACC[3][3] += (A4).w*(B4).w; \
} while (0)

__device__ __forceinline__ float bsum256(float v, float* red) {
#pragma unroll
  for (int off = 32; off; off >>= 1) v += __shfl_down(v, off);
  __syncthreads();
  if ((threadIdx.x & 63) == 0) red[threadIdx.x >> 6] = v;
  __syncthreads();
  return red[0] + red[1] + red[2] + red[3];
}

__device__ __forceinline__ float bmax256(float v, float* red) {
#pragma unroll
  for (int off = 32; off; off >>= 1) v = fmaxf(v, __shfl_down(v, off));
  __syncthreads();
  if ((threadIdx.x & 63) == 0) red[threadIdx.x >> 6] = v;
  __syncthreads();
  return fmaxf(fmaxf(red[0], red[1]), fmaxf(red[2], red[3]));
}

// C[M,N] = A[M,K] @ B^T (BT: B is [N,K]) or A @ B (else: B is [K,N]), + bias, opt ReLU.
// 64x64 tile, 256 threads, 4x4 accum/thread, K-step 16. All dims multiples of 64/16.
template <bool BT, bool RELU>
__global__ __launch_bounds__(256) void gemm64(const float* __restrict__ A,
                                              const float* __restrict__ Bm,
                                              const float* __restrict__ bias,
                                              float* __restrict__ C,
                                              int M, int N, int K) {
  __shared__ float As[16][68];
  __shared__ float Bs[16][68];
  const int t = threadIdx.x;
  const int m0 = blockIdx.x << 6;
  const int n0 = blockIdx.y << 6;
  const int r0 = (t >> 4) << 2;
  const int c0 = (t & 15) << 2;
  const int lm = t >> 2;
  const int lk4 = (t & 3) << 2;
  const int lkk = t >> 4;
  const int ln = (t & 15) << 2;
  float acc[4][4] = {{0.f, 0.f, 0.f, 0.f}, {0.f, 0.f, 0.f, 0.f},
                     {0.f, 0.f, 0.f, 0.f}, {0.f, 0.f, 0.f, 0.f}};
  for (int kt = 0; kt < K; kt += 16) {
    __syncthreads();
    float4 av = *reinterpret_cast<const float4*>(A + (size_t)(m0 + lm) * K + kt + lk4);
    As[lk4 + 0][lm] = av.x; As[lk4 + 1][lm] = av.y;
    As[lk4 + 2][lm] = av.z; As[lk4 + 3][lm] = av.w;
    if (BT) {
      float4 bv = *reinterpret_cast<const float4*>(Bm + (size_t)(n0 + lm) * K + kt + lk4);
      Bs[lk4 + 0][lm] = bv.x; Bs[lk4 + 1][lm] = bv.y;
      Bs[lk4 + 2][lm] = bv.z; Bs[lk4 + 3][lm] = bv.w;
    } else {
      float4 bv = *reinterpret_cast<const float4*>(Bm + (size_t)(kt + lkk) * N + n0 + ln);
      *reinterpret_cast<float4*>(&Bs[lkk][ln]) = bv;
    }
    __syncthreads();
#pragma unroll
    for (int k = 0; k < 16; ++k) {
      float4 a4 = *reinterpret_cast<const float4*>(&As[k][r0]);
      float4 b4 = *reinterpret_cast<const float4*>(&Bs[k][c0]);
      OUTER16(acc, a4, b4);
    }
  }
  float bb0 = 0.f, bb1 = 0.f, bb2 = 0.f, bb3 = 0.f;
  if (bias) {
    bb0 = bias[n0 + c0 + 0]; bb1 = bias[n0 + c0 + 1];
    bb2 = bias[n0 + c0 + 2]; bb3 = bias[n0 + c0 + 3];
  }
#pragma unroll
  for (int i = 0; i < 4; ++i) {
    float4 o;
    o.x = acc[i][0] + bb0; o.y = acc[i][1] + bb1;
    o.z = acc[i][2] + bb2; o.w = acc[i][3] + bb3;
    if (RELU) {
      o.x = fmaxf(o.x, 0.f); o.y = fmaxf(o.y, 0.f);
      o.z = fmaxf(o.z, 0.f); o.w = fmaxf(o.w, 0.f);
    }
    *reinterpret_cast<float4*>(C + (size_t)(m0 + r0 + i) * N + n0 + c0) = o;
  }
}

// Flash attention: qkv (B,S,1536) layout [q|k|v] each D=512, H=8 heads of 64.
// Grid (qblock=8, head=8, batch=32), 256 threads, QB=64 rows, online softmax.
__global__ __launch_bounds__(256) void flash_attn(const float* __restrict__ qkv,
                                                  float* __restrict__ ctx) {
  __shared__ float Qt[64][68];  // [d][qi]
  __shared__ float Kt[64][68];  // [d][kj]
  __shared__ float Vs[64][68];  // [kj][d]
  __shared__ float Pt[64][68];  // [kj][qi]
  const int qb = blockIdx.x, hh = blockIdx.y, b = blockIdx.z;
  const int t = threadIdx.x;
  const float* qbase = qkv + (size_t)(b * 512 + qb * 64) * 1536 + hh * 64;
  const float* kbase = qkv + (size_t)b * 512 * 1536 + 512 + hh * 64;
  const float* vbase = kbase + 512;
  {
    const int qi = t >> 2, d0 = (t & 3) << 4;
#pragma unroll
    for (int j = 0; j < 4; ++j) {
      float4 v = *reinterpret_cast<const float4*>(qbase + (size_t)qi * 1536 + d0 + 4 * j);
      Qt[d0 + 4 * j + 0][qi] = v.x; Qt[d0 + 4 * j + 1][qi] = v.y;
      Qt[d0 + 4 * j + 2][qi] = v.z; Qt[d0 + 4 * j + 3][qi] = v.w;
    }
  }
  const int r0 = (t >> 4) << 2, c0 = (t & 15) << 2;
  float m[4], l[4], acc[4][4];
#pragma unroll
  for (int i = 0; i < 4; ++i) {
    m[i] = -INFINITY; l[i] = 0.f;
    acc[i][0] = acc[i][1] = acc[i][2] = acc[i][3] = 0.f;
  }
  for (int kt = 0; kt < 8; ++kt) {
    __syncthreads();
    {
      const int r = t >> 2, d0 = (t & 3) << 4;
      const float* kp = kbase + (size_t)(kt * 64 + r) * 1536 + d0;
      const float* vp = vbase + (size_t)(kt * 64 + r) * 1536 + d0;
#pragma unroll
      for (int j = 0; j < 4; ++j) {
        float4 kv = *reinterpret_cast<const float4*>(kp + 4 * j);
        Kt[d0 + 4 * j + 0][r] = kv.x; Kt[d0 + 4 * j + 1][r] = kv.y;
        Kt[d0 + 4 * j + 2][r] = kv.z; Kt[d0 + 4 * j + 3][r] = kv.w;
        *reinterpret_cast<float4*>(&Vs[r][d0 + 4 * j]) =
            *reinterpret_cast<const float4*>(vp + 4 * j);
      }
    }
    __syncthreads();
    float s[4][4] = {{0.f, 0.f, 0.f, 0.f}, {0.f, 0.f, 0.f, 0.f},
                     {0.f, 0.f, 0.f, 0.f}, {0.f, 0.f, 0.f, 0.f}};
#pragma unroll 8
    for (int d = 0; d < 64; ++d) {
      float4 q4 = *reinterpret_cast<const float4*>(&Qt[d][r0]);
      float4 k4 = *reinterpret_cast<const float4*>(&Kt[d][c0]);
      OUTER16(s, q4, k4);
    }
#pragma unroll
    for (int i = 0; i < 4; ++i)
#pragma unroll
      for (int j = 0; j < 4; ++j) s[i][j] *= 0.125f;
    float rm[4];
#pragma unroll
    for (int i = 0; i < 4; ++i)
      rm[i] = fmaxf(fmaxf(s[i][0], s[i][1]), fmaxf(s[i][2], s[i][3]));
#pragma unroll
    for (int off = 1; off < 16; off <<= 1) {
#pragma unroll
      for (int i = 0; i < 4; ++i) rm[i] = fmaxf(rm[i], __shfl_xor(rm[i], off));
    }
    float al[4];
#pragma unroll
    for (int i = 0; i < 4; ++i) {
      float mn = fmaxf(m[i], rm[i]);
      al[i] = expf(m[i] - mn);
      m[i] = mn;
    }
    float p[4][4], rs[4];
#pragma unroll
    for (int i = 0; i < 4; ++i) {
#pragma unroll
      for (int j = 0; j < 4; ++j) p[i][j] = expf(s[i][j] - m[i]);
      rs[i] = p[i][0] + p[i][1] + p[i][2] + p[i][3];
    }
#pragma unroll
    for (int off = 1; off < 16; off <<= 1) {
#pragma unroll
      for (int i = 0; i < 4; ++i) rs[i] += __shfl_xor(rs[i], off);
    }
#pragma unroll
    for (int i = 0; i < 4; ++i) {
      l[i] = l[i] * al[i] + rs[i];
      acc[i][0] *= al[i]; acc[i][1] *= al[i]; acc[i][2] *= al[i]; acc[i][3] *= al[i];
    }
#pragma unroll
    for (int cj = 0; cj < 4; ++cj) {
      float4 o = make_float4(p[0][cj], p[1][cj], p[2][cj], p[3][cj]);
      *reinterpret_cast<float4*>(&Pt[c0 + cj][r0]) = o;
    }
    __syncthreads();
#pragma unroll 8
    for (int kj = 0; kj < 64; ++kj) {
      float4 p4 = *reinterpret_cast<const float4*>(&Pt[kj][r0]);
      float4 v4 = *reinterpret_cast<const float4*>(&Vs[kj][c0]);
      OUTER16(acc, p4, v4);
    }
  }
  float* obase = ctx + (size_t)(b * 512 + qb * 64) * 512 + hh * 64;
#pragma unroll
  for (int i = 0; i < 4; ++i) {
    float inv = 1.f / l[i];
    float4 o = make_float4(acc[i][0] * inv, acc[i][1] * inv, acc[i][2] * inv, acc[i][3] * inv);
    *reinterpret_cast<float4*>(obase + (size_t)(r0 + i) * 512 + c0) = o;
  }
}

// h = LN(h + res) * g + b, rows of 512, one row per block (256 threads).
__global__ __launch_bounds__(256) void ln_fused(float* __restrict__ h,
                                                const float* __restrict__ res,
                                                const float* __restrict__ g,
                                                const float* __restrict__ bt) {
  __shared__ float red[4];
  const size_t row = blockIdx.x;
  float* hp = h + row * 512;
  const float* rp = res + row * 512;
  const int t = threadIdx.x;
  float x0 = hp[t] + rp[t];
  float x1 = hp[t + 256] + rp[t + 256];
  float mean = bsum256(x0 + x1, red) * (1.f / 512.f);
  float d0 = x0 - mean, d1 = x1 - mean;
  float var = bsum256(d0 * d0 + d1 * d1, red) * (1.f / 512.f);
  float rstd = rsqrtf(var + 1e-5f);
  hp[t] = d0 * rstd * g[t] + bt[t];
  hp[t + 256] = d1 * rstd * g[t + 256] + bt[t + 256];
}

__global__ __launch_bounds__(256) void softmax1024(float* __restrict__ p) {
  __shared__ float red[4];
  float4* rp = reinterpret_cast<float4*>(p + (size_t)blockIdx.x * 1024);
  const int t = threadIdx.x;
  float4 v = rp[t];
  float mx = bmax256(fmaxf(fmaxf(v.x, v.y), fmaxf(v.z, v.w)), red);
  float e0 = expf(v.x - mx), e1 = expf(v.y - mx), e2 = expf(v.z - mx), e3 = expf(v.w - mx);
  float sm = bsum256(e0 + e1 + e2 + e3, red);
  float inv = 1.f / sm;
  rp[t] = make_float4(e0 * inv, e1 * inv, e2 * inv, e3 * inv);
}

// pe[s, 2i] = sin(s*div_i), pe[s, 2i+1] = cos(s*div_i), f64 math like numpy.
__global__ void pe_kernel(float* __restrict__ pe) {
  const int s = blockIdx.x, i = threadIdx.x;  // 512 x 256
  double div = exp((double)(2 * i) * (-log(10000.0) / 512.0));
  double a = (double)s * div;
  pe[s * 512 + 2 * i] = (float)sin(a);
  pe[s * 512 + 2 * i + 1] = (float)cos(a);
}

__global__ __launch_bounds__(256) void add_pe(float* __restrict__ h,
                                              const float* __restrict__ pe) {
  const size_t g = (size_t)blockIdx.x * 256 + threadIdx.x;  // 2,097,152 float4
  const int c4 = (int)(g & 127);
  const size_t mrow = g >> 7;
  const int s = (int)(mrow & 511);
  float4 v = reinterpret_cast<float4*>(h)[g];
  float4 p = reinterpret_cast<const float4*>(pe)[(size_t)s * 128 + c4];
  v.x += p.x; v.y += p.y; v.z += p.z; v.w += p.w;
  reinterpret_cast<float4*>(h)[g] = v;
}

__global__ __launch_bounds__(256) void cat_kernel(const float* __restrict__ h,
                                                  const float* __restrict__ u,
                                                  float* __restrict__ c) {
  const size_t g = (size_t)blockIdx.x * 256 + threadIdx.x;  // 4,194,304 float4
  const size_t mrow = g >> 8;
  const int c4 = (int)(g & 255);
  float4 v = (c4 < 128) ? reinterpret_cast<const float4*>(h)[mrow * 128 + c4]
                        : reinterpret_cast<const float4*>(u)[mrow * 128 + (c4 - 128)];
  reinterpret_cast<float4*>(c)[g] = v;
}

__global__ __launch_bounds__(256) void transpose_x(const float* __restrict__ x,
                                                   float* __restrict__ xt) {
  const size_t g = (size_t)blockIdx.x * 256 + threadIdx.x;  // 1,048,576
  const int s = (int)(g & 511);
  const int f = (int)((g >> 9) & 63);
  const int b = (int)(g >> 15);
  xt[g] = x[((size_t)b * 512 + s) * 64 + f];
}

// fn[b] = rownorm( mean_s x[b,s,:] ), 32 blocks x 64 threads.
__global__ void fmean_kernel(const float* __restrict__ x, float* __restrict__ fn) {
  const int b = blockIdx.x, f = threadIdx.x;
  float s = 0.f;
  const float* xp = x + (size_t)b * 512 * 64 + f;
  for (int i = 0; i < 512; ++i) s += xp[(size_t)i * 64];
  s *= (1.f / 512.f);
  float ss = s * s;
#pragma unroll
  for (int off = 32; off; off >>= 1) ss += __shfl_down(ss, off);
  ss = __shfl(ss, 0);
  float n = fmaxf(sqrtf(ss), 1e-12f);
  fn[b * 64 + f] = s / n;
}

// sim = outer(fn,fn); top-4 per row (strict > => lowest-index tie-break, like
// jax.lax.top_k), drop top-1, set A, symmetrize via max, diag=1, row-normalize.
__global__ void graph_kernel(const float* __restrict__ fn, float* __restrict__ An) {
  __shared__ float fv[64];
  __shared__ float Am[64][65];
  const int b = blockIdx.x, i = threadIdx.x;  // 32 blocks x 64 threads
  fv[i] = fn[b * 64 + i];
#pragma unroll
  for (int j = 0; j < 64; ++j) Am[i][j] = 0.f;
  __syncthreads();
  const float fi = fv[i];
  unsigned long long mask = 0ull;
  int sel[4];
  for (int t4 = 0; t4 < 4; ++t4) {
    float best = -INFINITY;
    int bi = 0;
    for (int j = 0; j < 64; ++j) {
      if (mask & (1ull << j)) continue;
      float v = fi * fv[j];
      if (v > best) { best = v; bi = j; }
    }
    mask |= (1ull << bi);
    sel[t4] = bi;
  }
  Am[i][sel[1]] = 1.f; Am[i][sel[2]] = 1.f; Am[i][sel[3]] = 1.f;
  __syncthreads();
  float deg = 0.f;
  for (int j = 0; j < 64; ++j) deg += (j == i) ? 1.f : fmaxf(Am[i][j], Am[j][i]);
  const float inv = 1.f / deg;
  float* out = An + ((size_t)b * 64 + i) * 64;
  for (int j = 0; j < 64; ++j)
    out[j] = ((j == i) ? 1.f : fmaxf(Am[i][j], Am[j][i])) * inv;
}

// Y[b,64,512-chunk] = An[b] (64x64) @ X[b] (64x512-chunk). Grid (8 chunks, 32 b).
template <bool RELU, bool STORE_T>
__global__ __launch_bounds__(256) void bmm_an(const float* __restrict__ An,
                                              const float* __restrict__ X,
                                              float* __restrict__ Y) {
  __shared__ float Ag[64][68];  // [g][i]
  __shared__ float Xs[64][68];  // [g][n]
  const int nc = blockIdx.x << 6;
  const int b = blockIdx.y;
  const int t = threadIdx.x;
  {
    const int i = t >> 2, g0 = (t & 3) << 4;
    const float* ap = An + ((size_t)b * 64 + i) * 64 + g0;
#pragma unroll
    for (int j = 0; j < 16; ++j) Ag[g0 + j][i] = ap[j];
  }
  {
    const int g = t >> 2, n4 = (t & 3) << 4;
    const float* xp = X + ((size_t)b * 64 + g) * 512 + nc + n4;
#pragma unroll
    for (int j = 0; j < 4; ++j)
      *reinterpret_cast<float4*>(&Xs[g][n4 + 4 * j]) =
          *reinterpret_cast<const float4*>(xp + 4 * j);
  }
  __syncthreads();
  const int r0 = (t >> 4) << 2, c0 = (t & 15) << 2;
  float acc[4][4] = {{0.f, 0.f, 0.f, 0.f}, {0.f, 0.f, 0.f, 0.f},
                     {0.f, 0.f, 0.f, 0.f}, {0.f, 0.f, 0.f, 0.f}};
#pragma unroll 8
  for (int g = 0; g < 64; ++g) {
    float4 a4 = *reinterpret_cast<const float4*>(&Ag[g][r0]);
    float4 x4 = *reinterpret_cast<const float4*>(&Xs[g][c0]);
    OUTER16(acc, a4, x4);
  }
  if (!STORE_T) {
#pragma unroll
    for (int i = 0; i < 4; ++i) {
      float4 o = make_float4(acc[i][0], acc[i][1], acc[i][2], acc[i][3]);
      if (RELU) {
        o.x = fmaxf(o.x, 0.f); o.y = fmaxf(o.y, 0.f);
        o.z = fmaxf(o.z, 0.f); o.w = fmaxf(o.w, 0.f);
      }
      *reinterpret_cast<float4*>(Y + ((size_t)b * 64 + r0 + i) * 512 + nc + c0) = o;
    }
  } else {
    // Y[b, s=nc+c0+j, f=r0..r0+3] = acc[:][j]
#pragma unroll
    for (int j = 0; j < 4; ++j) {
      float4 o = make_float4(acc[0][j], acc[1][j], acc[2][j], acc[3][j]);
      *reinterpret_cast<float4*>(Y + ((size_t)b * 512 + nc + c0 + j) * 64 + r0) = o;
    }
  }
}

}  // namespace

extern "C" void kernel_launch(void* const* d_in, const int* in_sizes, int n_in,
                              void* d_out, int out_size, void* d_ws, size_t ws_size,
                              hipStream_t stream) {
  const float* x     = (const float*)d_in[0];
  const float* W_in  = (const float*)d_in[1];
  const float* b_in  = (const float*)d_in[2];
  const float* qkv_w = (const float*)d_in[3];
  const float* qkv_b = (const float*)d_in[4];
  const float* out_w = (const float*)d_in[5];
  const float* out_b = (const float*)d_in[6];
  const float* ln1_g = (const float*)d_in[7];
  const float* ln1_b = (const float*)d_in[8];
  const float* ln2_g = (const float*)d_in[9];
  const float* ln2_b = (const float*)d_in[10];
  const float* ff1_w = (const float*)d_in[11];
  const float* ff1_b = (const float*)d_in[12];
  const float* ff2_w = (const float*)d_in[13];
  const float* ff2_b = (const float*)d_in[14];
  const float* memw  = (const float*)d_in[15];
  const float* fc1_w = (const float*)d_in[16];
  const float* fc1_b = (const float*)d_in[17];
  const float* fc2_w = (const float*)d_in[18];
  const float* fc2_b = (const float*)d_in[19];
  const float* gc1_w = (const float*)d_in[20];
  const float* gc1_b = (const float*)d_in[21];
  const float* gc2_w = (const float*)d_in[22];
  const float* gc2_b = (const float*)d_in[23];

  float* ws   = (float*)d_ws;
  float* h    = ws;                   // 8,388,608
  float* bufA = ws + 8388608;         // 33,554,432 (qkv / ff-mid / cat / gcn)
  float* bufB = bufA + 33554432;      // 8,388,608 (ctx / upd)
  float* bufC = bufB + 8388608;       // 8,388,608 (mha / ff2 / fc1out)
  float* pe   = bufC + 8388608;       // 262,144
  float* fn   = pe + 262144;          // 2,048
  float* An   = fn + 2048;            // 131,072
  // total ws: 59,115,520 floats = 236.5 MB

  float* t_out = (float*)d_out;            // 1,048,576
  float* g_out = t_out + 1048576;          // 1,048,576
  float* attn  = g_out + 1048576;          // 16,777,216

  hipLaunchKernelGGL(pe_kernel, dim3(512), dim3(256), 0, stream, pe);
  // h = x @ W_in.T + b_in   (16384x64 @ 64x512)
  hipLaunchKernelGGL((gemm64<true, false>), dim3(Mrows / 64, 8), dim3(256), 0, stream,
                     x, W_in, b_in, h, Mrows, 512, 64);
  hipLaunchKernelGGL(add_pe, dim3(8192), dim3(256), 0, stream, h, pe);

  for (int l = 0; l < 3; ++l) {
    hipLaunchKernelGGL((gemm64<true, false>), dim3(Mrows / 64, 24), dim3(256), 0, stream,
                       h, qkv_w + (size_t)l * 1536 * 512, qkv_b + l * 1536, bufA,
                       Mrows, 1536, 512);
    hipLaunchKernelGGL(flash_attn, dim3(8, 8, 32), dim3(256), 0, stream, bufA, bufB);
    hipLaunchKernelGGL((gemm64<true, false>), dim3(Mrows / 64, 8), dim3(256), 0, stream,
                       bufB, out_w + (size_t)l * 512 * 512, out_b + l * 512, bufC,
                       Mrows, 512, 512);
    hipLaunchKernelGGL(ln_fused, dim3(Mrows), dim3(256), 0, stream,
                       h, bufC, ln1_g + l * 512, ln1_b + l * 512);
    hipLaunchKernelGGL((gemm64<true, true>), dim3(Mrows / 64, 32), dim3(256), 0, stream,
                       h, ff1_w + (size_t)l * 2048 * 512, ff1_b + l * 2048, bufA,
                       Mrows, 2048, 512);
    hipLaunchKernelGGL((gemm64<true, false>), dim3(Mrows / 64, 8), dim3(256), 0, stream,
                       bufA, ff2_w + (size_t)l * 512 * 2048, ff2_b + l * 512, bufC,
                       Mrows, 512, 2048);
    hipLaunchKernelGGL(ln_fused, dim3(Mrows), dim3(256), 0, stream,
                       h, bufC, ln2_g + l * 512, ln2_b + l * 512);
  }

  // sims = h @ memory.T (TEMP=1), softmax in place in d_out's attn region.
  hipLaunchKernelGGL((gemm64<true, false>), dim3(Mrows / 64, 16), dim3(256), 0, stream,
                     h, memw, (const float*)nullptr, attn, Mrows, 1024, 512);
  hipLaunchKernelGGL(softmax1024, dim3(Mrows), dim3(256), 0, stream, attn);
  // upd = attn @ memory  (NN: B is [1024,512])
  hipLaunchKernelGGL((gemm64<false, false>), dim3(Mrows / 64, 8), dim3(256), 0, stream,
                     attn, memw, (const float*)nullptr, bufB, Mrows, 512, 1024);
  hipLaunchKernelGGL(cat_kernel, dim3(16384), dim3(256), 0, stream, h, bufB, bufA);
  hipLaunchKernelGGL((gemm64<true, true>), dim3(Mrows / 64, 8), dim3(256), 0, stream,
                     bufA, fc1_w, fc1_b, bufC, Mrows, 512, 1024);
  hipLaunchKernelGGL((gemm64<true, false>), dim3(Mrows / 64, 1), dim3(256), 0, stream,
                     bufC, fc2_w, fc2_b, t_out, Mrows, 64, 512);

  // GCN branch (independent of transformer; reuses bufA after t_out done).
  hipLaunchKernelGGL(fmean_kernel, dim3(32), dim3(64), 0, stream, x, fn);
  hipLaunchKernelGGL(graph_kernel, dim3(32), dim3(64), 0, stream, fn, An);
  float* xt = bufA;                 // 1,048,576 each
  float* t1 = bufA + 1048576;
  float* h1 = bufA + 2097152;
  float* t2 = bufA + 3145728;
  hipLaunchKernelGGL(transpose_x, dim3(4096), dim3(256), 0, stream, x, xt);
  hipLaunchKernelGGL((gemm64<true, false>), dim3(2048 / 64, 8), dim3(256), 0, stream,
                     xt, gc1_w, gc1_b, t1, 2048, 512, 512);
  hipLaunchKernelGGL((bmm_an<true, false>), dim3(8, 32), dim3(256), 0, stream, An, t1, h1);
  hipLaunchKernelGGL((gemm64<true, false>), dim3(2048 / 64, 8), dim3(256), 0, stream,
                     h1, gc2_w, gc2_b, t2, 2048, 512, 512);
  hipLaunchKernelGGL((bmm_an<false, true>), dim3(8, 32), dim3(256), 0, stream, An, t2, g_out);
}

// Round 2
// 1928.714 us; speedup vs baseline: 3.6151x; 3.6151x over previous
//
#include <hip/hip_runtime.h>
#include <hip/hip_bf16.h>
#include <math.h>

// METG forward. Round 2: big GEMMs -> bf16 MFMA (m97-style 128x128 tile,
// global_load_lds staging, XOR-swizzled LDS). Flash-attn / LN / GCN stay f32.
// Shapes: B=32 S=512 F_IN=64 D=512 DFF=2048 MEM=1024 L=3 H=8 DH=64

namespace {

typedef unsigned short ushort_t;
using bf16x8 = __attribute__((ext_vector_type(8))) __bf16;
using f32x4 = __attribute__((ext_vector_type(4))) float;

constexpr int Mrows = 32 * 512;  // 16384

__device__ __forceinline__ unsigned short f2bf(float f) {
  unsigned int u = __builtin_bit_cast(unsigned int, f);
  u += 0x7fffu + ((u >> 16) & 1u);
  return (unsigned short)(u >> 16);
}

__device__ __forceinline__ void g2lds16(const void* g, void* l) {
  __builtin_amdgcn_global_load_lds(
      (const __attribute__((address_space(1))) unsigned int*)g,
      (__attribute__((address_space(3))) unsigned int*)l, 16, 0, 0);
}

// ---------------- bf16 MFMA GEMM: C[M,N] = A[M,K] @ B[N,K]^T (+bias, opt relu)
// 128x128 tile, BK=64, 256 threads = 4 waves (2x2), 4x4 16x16x32 frags/wave.
// LDS linear [row][64] bf16 with XOR bank-swizzle applied via pre-swizzled
// global source (staging) + swizzled ds_read (fragments). 2-way conflicts only.
template <bool RELU, bool BF16OUT>
__global__ __launch_bounds__(256) void gemm_bf16(const ushort_t* __restrict__ A,
                                                 const ushort_t* __restrict__ B,
                                                 const float* __restrict__ bias,
                                                 void* __restrict__ Cv,
                                                 int M, int N, int K) {
  __shared__ __align__(16) ushort_t As[128 * 64];
  __shared__ __align__(16) ushort_t Bs[128 * 64];
  const int t = threadIdx.x;
  const int w = t >> 6, l = t & 63;
  const int m0 = blockIdx.x << 7, n0 = blockIdx.y << 7;
  // staging: wave w stages rows [w*32, w*32+32) of both tiles; 4 instrs each.
  // LDS linear byte (row*128 + slot*16) holds global k-slice (slot ^ (row&7)).
  const int srow = w * 32 + (l >> 3);
  const int scol = ((l & 7) ^ (l >> 3)) << 3;  // element offset (8 elems/slot)
  const ushort_t* agp = A + (size_t)(m0 + srow) * K + scol;
  const ushort_t* bgp = B + (size_t)(n0 + srow) * K + scol;
  ushort_t* alds = &As[(w * 32) * 64];
  ushort_t* blds = &Bs[(w * 32) * 64];
  // fragments
  const int wr = w >> 1, wc = w & 1;
  const int lr = l & 15, g = l >> 4;
  const int sw = (l & 7) << 4;  // byte swizzle (row&7 == l&7 for frag rows)
  f32x4 acc[4][4] = {};
  for (int kt = 0; kt < K; kt += 64) {
    __syncthreads();
#pragma unroll
    for (int i = 0; i < 4; ++i) {
      g2lds16(agp + (size_t)(i * 8) * K + kt, alds + i * 8 * 64);
      g2lds16(bgp + (size_t)(i * 8) * K + kt, blds + i * 8 * 64);
    }
    __syncthreads();  // compiler drains vmcnt before barrier
#pragma unroll
    for (int ki = 0; ki < 2; ++ki) {
      bf16x8 af[4], bf[4];
      const int kb = (ki * 64 + g * 16) ^ sw;
#pragma unroll
      for (int mi = 0; mi < 4; ++mi)
        af[mi] = *(const bf16x8*)((const char*)As + (wr * 64 + mi * 16 + lr) * 128 + kb);
#pragma unroll
      for (int ni = 0; ni < 4; ++ni)
        bf[ni] = *(const bf16x8*)((const char*)Bs + (wc * 64 + ni * 16 + lr) * 128 + kb);
#pragma unroll
      for (int mi = 0; mi < 4; ++mi)
#pragma unroll
        for (int ni = 0; ni < 4; ++ni)
          acc[mi][ni] = __builtin_amdgcn_mfma_f32_16x16x32_bf16(af[mi], bf[ni],
                                                                acc[mi][ni], 0, 0, 0);
    }
  }
  float bb[4];
#pragma unroll
  for (int ni = 0; ni < 4; ++ni)
    bb[ni] = bias ? bias[n0 + wc * 64 + ni * 16 + lr] : 0.f;
  const int crow0 = m0 + wr * 64 + g * 4;
  const int ccol0 = n0 + wc * 64 + lr;
  if (!BF16OUT) {
    float* Cf = (float*)Cv;
#pragma unroll
    for (int mi = 0; mi < 4; ++mi)
#pragma unroll
      for (int ni = 0; ni < 4; ++ni)
#pragma unroll
        for (int v = 0; v < 4; ++v) {
          float val = acc[mi][ni][v] + bb[ni];
          if (RELU) val = fmaxf(val, 0.f);
          Cf[(size_t)(crow0 + mi * 16 + v) * N + ccol0 + ni * 16] = val;
        }
  } else {
    ushort_t* Cb = (ushort_t*)Cv;
#pragma unroll
    for (int mi = 0; mi < 4; ++mi)
#pragma unroll
      for (int ni = 0; ni < 4; ++ni)
#pragma unroll
        for (int v = 0; v < 4; ++v) {
          float val = acc[mi][ni][v] + bb[ni];
          if (RELU) val = fmaxf(val, 0.f);
          Cb[(size_t)(crow0 + mi * 16 + v) * N + ccol0 + ni * 16] = f2bf(val);
        }
  }
}

// ---------------- f32 fallback GEMM (small ops): C = A @ B^T + bias, opt relu
#define OUTER16(ACC, A4, B4) do { \
  ACC[0][0] += (A4).x*(B4).x; ACC[0][1] += (A4).x*(B4).y; ACC[0][2] += (A4).x*(B4).z; ACC[0][3] += (A4).x*(B4).w; \
  ACC[1][0] += (A4).y*(B4).x; ACC[1][1] += (A4).y*(B4).y; ACC[1][2] += (A4).y*(B4).z; ACC[1][3] += (A4).y*(B4).w; \
  ACC[2][0] += (A4).z*(B4).x; ACC[2][1] += (A4).z*(B4).y; ACC[2][2] += (A4).z*(B4).z; ACC[2][3] += (A4).z*(B4).w; \
  ACC[3][0] += (A4).w*(B4).x; ACC[3][1] += (A4).w*(B4).y; ACC[3][2] += (A4).w*(B4).z; ACC[3][3] += (A4).w*(B4).w; \
} while (0)

template <bool BT, bool RELU>
__global__ __launch_bounds__(256) void gemm64(const float* __restrict__ A,
                                              const float* __restrict__ Bm,
                                              const float* __restrict__ bias,
                                              float* __restrict__ C,
                                              int M, int N, int K) {
  __shared__ float As[16][68];
  __shared__ float Bs[16][68];
  const int t = threadIdx.x;
  const int m0 = blockIdx.x << 6;
  const int n0 = blockIdx.y << 6;
  const int r0 = (t >> 4) << 2;
  const int c0 = (t & 15) << 2;
  const int lm = t >> 2;
  const int lk4 = (t & 3) << 2;
  const int lkk = t >> 4;
  const int ln = (t & 15) << 2;
  float acc[4][4] = {{0.f, 0.f, 0.f, 0.f}, {0.f, 0.f, 0.f, 0.f},
                     {0.f, 0.f, 0.f, 0.f}, {0.f, 0.f, 0.f, 0.f}};
  for (int kt = 0; kt < K; kt += 16) {
    __syncthreads();
    float4 av = *reinterpret_cast<const float4*>(A + (size_t)(m0 + lm) * K + kt + lk4);
    As[lk4 + 0][lm] = av.x; As[lk4 + 1][lm] = av.y;
    As[lk4 + 2][lm] = av.z; As[lk4 + 3][lm] = av.w;
    if (BT) {
      float4 bv = *reinterpret_cast<const float4*>(Bm + (size_t)(n0 + lm) * K + kt + lk4);
      Bs[lk4 + 0][lm] = bv.x; Bs[lk4 + 1][lm] = bv.y;
      Bs[lk4 + 2][lm] = bv.z; Bs[lk4 + 3][lm] = bv.w;
    } else {
      float4 bv = *reinterpret_cast<const float4*>(Bm + (size_t)(kt + lkk) * N + n0 + ln);
      *reinterpret_cast<float4*>(&Bs[lkk][ln]) = bv;
    }
    __syncthreads();
#pragma unroll
    for (int k = 0; k < 16; ++k) {
      float4 a4 = *reinterpret_cast<const float4*>(&As[k][r0]);
      float4 b4 = *reinterpret_cast<const float4*>(&Bs[k][c0]);
      OUTER16(acc, a4, b4);
    }
  }
  float bb0 = 0.f, bb1 = 0.f, bb2 = 0.f, bb3 = 0.f;
  if (bias) {
    bb0 = bias[n0 + c0 + 0]; bb1 = bias[n0 + c0 + 1];
    bb2 = bias[n0 + c0 + 2]; bb3 = bias[n0 + c0 + 3];
  }
#pragma unroll
  for (int i = 0; i < 4; ++i) {
    float4 o;
    o.x = acc[i][0] + bb0; o.y = acc[i][1] + bb1;
    o.z = acc[i][2] + bb2; o.w = acc[i][3] + bb3;
    if (RELU) {
      o.x = fmaxf(o.x, 0.f); o.y = fmaxf(o.y, 0.f);
      o.z = fmaxf(o.z, 0.f); o.w = fmaxf(o.w, 0.f);
    }
    *reinterpret_cast<float4*>(C + (size_t)(m0 + r0 + i) * N + n0 + c0) = o;
  }
}

// ---------------- flash attention (f32 math, bf16 ctx out)
__global__ __launch_bounds__(256) void flash_attn(const float* __restrict__ qkv,
                                                  ushort_t* __restrict__ ctxb) {
  __shared__ float Qt[64][68];
  __shared__ float Kt[64][68];
  __shared__ float Vs[64][68];
  __shared__ float Pt[64][68];
  const int qb = blockIdx.x, hh = blockIdx.y, b = blockIdx.z;
  const int t = threadIdx.x;
  const float* qbase = qkv + (size_t)(b * 512 + qb * 64) * 1536 + hh * 64;
  const float* kbase = qkv + (size_t)b * 512 * 1536 + 512 + hh * 64;
  const float* vbase = kbase + 512;
  {
    const int qi = t >> 2, d0 = (t & 3) << 4;
#pragma unroll
    for (int j = 0; j < 4; ++j) {
      float4 v = *reinterpret_cast<const float4*>(qbase + (size_t)qi * 1536 + d0 + 4 * j);
      Qt[d0 + 4 * j + 0][qi] = v.x; Qt[d0 + 4 * j + 1][qi] = v.y;
      Qt[d0 + 4 * j + 2][qi] = v.z; Qt[d0 + 4 * j + 3][qi] = v.w;
    }
  }
  const int r0 = (t >> 4) << 2, c0 = (t & 15) << 2;
  float m[4], l[4], acc[4][4];
#pragma unroll
  for (int i = 0; i < 4; ++i) {
    m[i] = -INFINITY; l[i] = 0.f;
    acc[i][0] = acc[i][1] = acc[i][2] = acc[i][3] = 0.f;
  }
  for (int kt = 0; kt < 8; ++kt) {
    __syncthreads();
    {
      const int r = t >> 2, d0 = (t & 3) << 4;
      const float* kp = kbase + (size_t)(kt * 64 + r) * 1536 + d0;
      const float* vp = vbase + (size_t)(kt * 64 + r) * 1536 + d0;
#pragma unroll
      for (int j = 0; j < 4; ++j) {
        float4 kv = *reinterpret_cast<const float4*>(kp + 4 * j);
        Kt[d0 + 4 * j + 0][r] = kv.x; Kt[d0 + 4 * j + 1][r] = kv.y;
        Kt[d0 + 4 * j + 2][r] = kv.z; Kt[d0 + 4 * j + 3][r] = kv.w;
        *reinterpret_cast<float4*>(&Vs[r][d0 + 4 * j]) =
            *reinterpret_cast<const float4*>(vp + 4 * j);
      }
    }
    __syncthreads();
    float s[4][4] = {{0.f, 0.f, 0.f, 0.f}, {0.f, 0.f, 0.f, 0.f},
                     {0.f, 0.f, 0.f, 0.f}, {0.f, 0.f, 0.f, 0.f}};
#pragma unroll 8
    for (int d = 0; d < 64; ++d) {
      float4 q4 = *reinterpret_cast<const float4*>(&Qt[d][r0]);
      float4 k4 = *reinterpret_cast<const float4*>(&Kt[d][c0]);
      OUTER16(s, q4, k4);
    }
#pragma unroll
    for (int i = 0; i < 4; ++i)
#pragma unroll
      for (int j = 0; j < 4; ++j) s[i][j] *= 0.125f;
    float rm[4];
#pragma unroll
    for (int i = 0; i < 4; ++i)
      rm[i] = fmaxf(fmaxf(s[i][0], s[i][1]), fmaxf(s[i][2], s[i][3]));
#pragma unroll
    for (int off = 1; off < 16; off <<= 1) {
#pragma unroll
      for (int i = 0; i < 4; ++i) rm[i] = fmaxf(rm[i], __shfl_xor(rm[i], off));
    }
    float al[4];
#pragma unroll
    for (int i = 0; i < 4; ++i) {
      float mn = fmaxf(m[i], rm[i]);
      al[i] = expf(m[i] - mn);
      m[i] = mn;
    }
    float p[4][4], rs[4];
#pragma unroll
    for (int i = 0; i < 4; ++i) {
#pragma unroll
      for (int j = 0; j < 4; ++j) p[i][j] = expf(s[i][j] - m[i]);
      rs[i] = p[i][0] + p[i][1] + p[i][2] + p[i][3];
    }
#pragma unroll
    for (int off = 1; off < 16; off <<= 1) {
#pragma unroll
      for (int i = 0; i < 4; ++i) rs[i] += __shfl_xor(rs[i], off);
    }
#pragma unroll
    for (int i = 0; i < 4; ++i) {
      l[i] = l[i] * al[i] + rs[i];
      acc[i][0] *= al[i]; acc[i][1] *= al[i]; acc[i][2] *= al[i]; acc[i][3] *= al[i];
    }
#pragma unroll
    for (int cj = 0; cj < 4; ++cj) {
      float4 o = make_float4(p[0][cj], p[1][cj], p[2][cj], p[3][cj]);
      *reinterpret_cast<float4*>(&Pt[c0 + cj][r0]) = o;
    }
    __syncthreads();
#pragma unroll 8
    for (int kj = 0; kj < 64; ++kj) {
      float4 p4 = *reinterpret_cast<const float4*>(&Pt[kj][r0]);
      float4 v4 = *reinterpret_cast<const float4*>(&Vs[kj][c0]);
      OUTER16(acc, p4, v4);
    }
  }
  ushort_t* obase = ctxb + (size_t)(b * 512 + qb * 64) * 512 + hh * 64;
#pragma unroll
  for (int i = 0; i < 4; ++i) {
    float inv = 1.f / l[i];
    ushort4 o;
    o.x = f2bf(acc[i][0] * inv); o.y = f2bf(acc[i][1] * inv);
    o.z = f2bf(acc[i][2] * inv); o.w = f2bf(acc[i][3] * inv);
    *reinterpret_cast<ushort4*>(obase + (size_t)(r0 + i) * 512 + c0) = o;
  }
}

__device__ __forceinline__ float bsum256(float v, float* red) {
#pragma unroll
  for (int off = 32; off; off >>= 1) v += __shfl_down(v, off);
  __syncthreads();
  if ((threadIdx.x & 63) == 0) red[threadIdx.x >> 6] = v;
  __syncthreads();
  return red[0] + red[1] + red[2] + red[3];
}

__device__ __forceinline__ float bmax256(float v, float* red) {
#pragma unroll
  for (int off = 32; off; off >>= 1) v = fmaxf(v, __shfl_down(v, off));
  __syncthreads();
  if ((threadIdx.x & 63) == 0) red[threadIdx.x >> 6] = v;
  __syncthreads();
  return fmaxf(fmaxf(red[0], red[1]), fmaxf(red[2], red[3]));
}

// h = LN(h + res); writes f32 h and bf16 hb.
__global__ __launch_bounds__(256) void ln_fused(float* __restrict__ h,
                                                ushort_t* __restrict__ hb,
                                                const float* __restrict__ res,
                                                const float* __restrict__ g,
                                                const float* __restrict__ bt) {
  __shared__ float red[4];
  const size_t row = blockIdx.x;
  float* hp = h + row * 512;
  ushort_t* hbp = hb + row * 512;
  const float* rp = res + row * 512;
  const int t = threadIdx.x;
  float x0 = hp[t] + rp[t];
  float x1 = hp[t + 256] + rp[t + 256];
  float mean = bsum256(x0 + x1, red) * (1.f / 512.f);
  float d0 = x0 - mean, d1 = x1 - mean;
  float var = bsum256(d0 * d0 + d1 * d1, red) * (1.f / 512.f);
  float rstd = rsqrtf(var + 1e-5f);
  float y0 = d0 * rstd * g[t] + bt[t];
  float y1 = d1 * rstd * g[t + 256] + bt[t + 256];
  hp[t] = y0; hp[t + 256] = y1;
  hbp[t] = f2bf(y0); hbp[t + 256] = f2bf(y1);
}

__global__ __launch_bounds__(256) void softmax1024(float* __restrict__ p) {
  __shared__ float red[4];
  float4* rp = reinterpret_cast<float4*>(p + (size_t)blockIdx.x * 1024);
  const int t = threadIdx.x;
  float4 v = rp[t];
  float mx = bmax256(fmaxf(fmaxf(v.x, v.y), fmaxf(v.z, v.w)), red);
  float e0 = expf(v.x - mx), e1 = expf(v.y - mx), e2 = expf(v.z - mx), e3 = expf(v.w - mx);
  float sm = bsum256(e0 + e1 + e2 + e3, red);
  float inv = 1.f / sm;
  rp[t] = make_float4(e0 * inv, e1 * inv, e2 * inv, e3 * inv);
}

__global__ void pe_kernel(float* __restrict__ pe) {
  const int s = blockIdx.x, i = threadIdx.x;
  double div = exp((double)(2 * i) * (-log(10000.0) / 512.0));
  double a = (double)s * div;
  pe[s * 512 + 2 * i] = (float)sin(a);
  pe[s * 512 + 2 * i + 1] = (float)cos(a);
}

__global__ __launch_bounds__(256) void add_pe(float* __restrict__ h,
                                              ushort_t* __restrict__ hb,
                                              const float* __restrict__ pe) {
  const size_t g = (size_t)blockIdx.x * 256 + threadIdx.x;  // float4 index
  const int c4 = (int)(g & 127);
  const size_t mrow = g >> 7;
  const int s = (int)(mrow & 511);
  float4 v = reinterpret_cast<float4*>(h)[g];
  float4 p = reinterpret_cast<const float4*>(pe)[(size_t)s * 128 + c4];
  v.x += p.x; v.y += p.y; v.z += p.z; v.w += p.w;
  reinterpret_cast<float4*>(h)[g] = v;
  ushort4 o;
  o.x = f2bf(v.x); o.y = f2bf(v.y); o.z = f2bf(v.z); o.w = f2bf(v.w);
  reinterpret_cast<ushort4*>(hb)[g] = o;
}

__global__ __launch_bounds__(256) void cvt_bf16(const float* __restrict__ in,
                                                ushort_t* __restrict__ out, int n4) {
  const int g = blockIdx.x * 256 + threadIdx.x;
  if (g >= n4) return;
  float4 v = reinterpret_cast<const float4*>(in)[g];
  ushort4 o;
  o.x = f2bf(v.x); o.y = f2bf(v.y); o.z = f2bf(v.z); o.w = f2bf(v.w);
  reinterpret_cast<ushort4*>(out)[g] = o;
}

// memory [1024,512] f32 -> memT bf16 [512,1024]
__global__ __launch_bounds__(256) void transpose_cvt(const float* __restrict__ in,
                                                     ushort_t* __restrict__ out) {
  const int g = blockIdx.x * 256 + threadIdx.x;  // 524288
  const int r = g >> 9, c = g & 511;
  out[(size_t)c * 1024 + r] = f2bf(in[g]);
}

// cat = [hb | updb] bf16, 16B chunks.
__global__ __launch_bounds__(256) void cat_bf16(const ushort_t* __restrict__ hb,
                                                const ushort_t* __restrict__ ub,
                                                ushort_t* __restrict__ cb) {
  const size_t g = (size_t)blockIdx.x * 256 + threadIdx.x;  // 16384*128 uint4
  const size_t mrow = g >> 7;
  const int c = (int)(g & 127);
  uint4 v = (c < 64) ? reinterpret_cast<const uint4*>(hb)[mrow * 64 + c]
                     : reinterpret_cast<const uint4*>(ub)[mrow * 64 + (c - 64)];
  reinterpret_cast<uint4*>(cb)[g] = v;
}

__global__ __launch_bounds__(256) void transpose_x(const float* __restrict__ x,
                                                   float* __restrict__ xt) {
  const size_t g = (size_t)blockIdx.x * 256 + threadIdx.x;
  const int s = (int)(g & 511);
  const int f = (int)((g >> 9) & 63);
  const int b = (int)(g >> 15);
  xt[g] = x[((size_t)b * 512 + s) * 64 + f];
}

__global__ void fmean_kernel(const float* __restrict__ x, float* __restrict__ fn) {
  const int b = blockIdx.x, f = threadIdx.x;
  float s = 0.f;
  const float* xp = x + (size_t)b * 512 * 64 + f;
  for (int i = 0; i < 512; ++i) s += xp[(size_t)i * 64];
  s *= (1.f / 512.f);
  float ss = s * s;
#pragma unroll
  for (int off = 32; off; off >>= 1) ss += __shfl_down(ss, off);
  ss = __shfl(ss, 0);
  float n = fmaxf(sqrtf(ss), 1e-12f);
  fn[b * 64 + f] = s / n;
}

__global__ void graph_kernel(const float* __restrict__ fn, float* __restrict__ An) {
  __shared__ float fv[64];
  __shared__ float Am[64][65];
  const int b = blockIdx.x, i = threadIdx.x;
  fv[i] = fn[b * 64 + i];
#pragma unroll
  for (int j = 0; j < 64; ++j) Am[i][j] = 0.f;
  __syncthreads();
  const float fi = fv[i];
  unsigned long long mask = 0ull;
  int sel[4];
  for (int t4 = 0; t4 < 4; ++t4) {
    float best = -INFINITY;
    int bi = 0;
    for (int j = 0; j < 64; ++j) {
      if (mask & (1ull << j)) continue;
      float v = fi * fv[j];
      if (v > best) { best = v; bi = j; }
    }
    mask |= (1ull << bi);
    sel[t4] = bi;
  }
  Am[i][sel[1]] = 1.f; Am[i][sel[2]] = 1.f; Am[i][sel[3]] = 1.f;
  __syncthreads();
  float deg = 0.f;
  for (int j = 0; j < 64; ++j) deg += (j == i) ? 1.f : fmaxf(Am[i][j], Am[j][i]);
  const float inv = 1.f / deg;
  float* out = An + ((size_t)b * 64 + i) * 64;
  for (int j = 0; j < 64; ++j)
    out[j] = ((j == i) ? 1.f : fmaxf(Am[i][j], Am[j][i])) * inv;
}

template <bool RELU, bool STORE_T>
__global__ __launch_bounds__(256) void bmm_an(const float* __restrict__ An,
                                              const float* __restrict__ X,
                                              float* __restrict__ Y) {
  __shared__ float Ag[64][68];
  __shared__ float Xs[64][68];
  const int nc = blockIdx.x << 6;
  const int b = blockIdx.y;
  const int t = threadIdx.x;
  {
    const int i = t >> 2, g0 = (t & 3) << 4;
    const float* ap = An + ((size_t)b * 64 + i) * 64 + g0;
#pragma unroll
    for (int j = 0; j < 16; ++j) Ag[g0 + j][i] = ap[j];
  }
  {
    const int g = t >> 2, n4 = (t & 3) << 4;
    const float* xp = X + ((size_t)b * 64 + g) * 512 + nc + n4;
#pragma unroll
    for (int j = 0; j < 4; ++j)
      *reinterpret_cast<float4*>(&Xs[g][n4 + 4 * j]) =
          *reinterpret_cast<const float4*>(xp + 4 * j);
  }
  __syncthreads();
  const int r0 = (t >> 4) << 2, c0 = (t & 15) << 2;
  float acc[4][4] = {{0.f, 0.f, 0.f, 0.f}, {0.f, 0.f, 0.f, 0.f},
                     {0.f, 0.f, 0.f, 0.f}, {0.f, 0.f, 0.f, 0.f}};
#pragma unroll 8
  for (int g = 0; g < 64; ++g) {
    float4 a4 = *reinterpret_cast<const float4*>(&Ag[g][r0]);
    float4 x4 = *reinterpret_cast<const float4*>(&Xs[g][c0]);
    OUTER16(acc, a4, x4);
  }
  if (!STORE_T) {
#pragma unroll
    for (int i = 0; i < 4; ++i) {
      float4 o = make_float4(acc[i][0], acc[i][1], acc[i][2], acc[i][3]);
      if (RELU) {
        o.x = fmaxf(o.x, 0.f); o.y = fmaxf(o.y, 0.f);
        o.z = fmaxf(o.z, 0.f); o.w = fmaxf(o.w, 0.f);
      }
      *reinterpret_cast<float4*>(Y + ((size_t)b * 64 + r0 + i) * 512 + nc + c0) = o;
    }
  } else {
#pragma unroll
    for (int j = 0; j < 4; ++j) {
      float4 o = make_float4(acc[0][j], acc[1][j], acc[2][j], acc[3][j]);
      *reinterpret_cast<float4*>(Y + ((size_t)b * 512 + nc + c0 + j) * 64 + r0) = o;
    }
  }
}

}  // namespace

extern "C" void kernel_launch(void* const* d_in, const int* in_sizes, int n_in,
                              void* d_out, int out_size, void* d_ws, size_t ws_size,
                              hipStream_t stream) {
  const float* x     = (const float*)d_in[0];
  const float* W_in  = (const float*)d_in[1];
  const float* b_in  = (const float*)d_in[2];
  const float* qkv_w = (const float*)d_in[3];
  const float* qkv_b = (const float*)d_in[4];
  const float* out_w = (const float*)d_in[5];
  const float* out_b = (const float*)d_in[6];
  const float* ln1_g = (const float*)d_in[7];
  const float* ln1_b = (const float*)d_in[8];
  const float* ln2_g = (const float*)d_in[9];
  const float* ln2_b = (const float*)d_in[10];
  const float* ff1_w = (const float*)d_in[11];
  const float* ff1_b = (const float*)d_in[12];
  const float* ff2_w = (const float*)d_in[13];
  const float* ff2_b = (const float*)d_in[14];
  const float* memw  = (const float*)d_in[15];
  const float* fc1_w = (const float*)d_in[16];
  const float* fc1_b = (const float*)d_in[17];
  const float* fc2_w = (const float*)d_in[18];
  const float* fc2_b = (const float*)d_in[19];
  const float* gc1_w = (const float*)d_in[20];
  const float* gc1_b = (const float*)d_in[21];
  const float* gc2_w = (const float*)d_in[22];
  const float* gc2_b = (const float*)d_in[23];

  char* wsb = (char*)d_ws;
  float*    h      = (float*)(wsb + 0);               // 32MB
  ushort_t* hb     = (ushort_t*)(wsb + 33554432);     // 16MB
  char*     U1     = wsb + 50331648;                  // 96MB shared region
  ushort_t* ctxb   = (ushort_t*)(wsb + 150994944);    // 16MB
  float*    bufC   = (float*)(wsb + 167772160);       // 32MB
  float*    pe     = (float*)(wsb + 201326592);       // 1MB
  ushort_t* qkv_wb = (ushort_t*)(wsb + 202375168);    // 4.5MB
  ushort_t* out_wb = (ushort_t*)(wsb + 207093760);    // 1.5MB
  ushort_t* ff1_wb = (ushort_t*)(wsb + 208666624);    // 6MB
  ushort_t* ff2_wb = (ushort_t*)(wsb + 214958080);    // 6MB
  ushort_t* mem_b  = (ushort_t*)(wsb + 221249536);    // 1MB
  ushort_t* memT_b = (ushort_t*)(wsb + 222298112);    // 1MB
  ushort_t* fc1_wb = (ushort_t*)(wsb + 223346688);    // 1MB
  float*    fn     = (float*)(wsb + 224395264);       // 8KB
  float*    An     = (float*)(wsb + 224403456);       // 512KB  (ends ~224.9MB)

  // U1 overlays (sequentially dead):
  float*    qkvf  = (float*)U1;                        // 96MB  (per-layer)
  ushort_t* midb  = (ushort_t*)U1;                     // 64MB  (ff1 out)
  ushort_t* attnb = (ushort_t*)U1;                     // 32MB
  ushort_t* catb  = (ushort_t*)(U1 + 33554432);        // 32MB
  ushort_t* updb  = (ushort_t*)(U1 + 67108864);        // 16MB
  float*    u1f   = (float*)U1;                        // GCN scratch

  float* t_out = (float*)d_out;
  float* g_out = t_out + 1048576;
  float* attn  = g_out + 1048576;

  // ---- weight conversions (cheap, every call)
  hipLaunchKernelGGL(cvt_bf16, dim3(2304), dim3(256), 0, stream, qkv_w, qkv_wb, 589824);
  hipLaunchKernelGGL(cvt_bf16, dim3(768), dim3(256), 0, stream, out_w, out_wb, 196608);
  hipLaunchKernelGGL(cvt_bf16, dim3(3072), dim3(256), 0, stream, ff1_w, ff1_wb, 786432);
  hipLaunchKernelGGL(cvt_bf16, dim3(3072), dim3(256), 0, stream, ff2_w, ff2_wb, 786432);
  hipLaunchKernelGGL(cvt_bf16, dim3(512), dim3(256), 0, stream, memw, mem_b, 131072);
  hipLaunchKernelGGL(cvt_bf16, dim3(512), dim3(256), 0, stream, fc1_w, fc1_wb, 131072);
  hipLaunchKernelGGL(transpose_cvt, dim3(2048), dim3(256), 0, stream, memw, memT_b);
  hipLaunchKernelGGL(pe_kernel, dim3(512), dim3(256), 0, stream, pe);

  // ---- input projection (f32) + positional encoding
  hipLaunchKernelGGL((gemm64<true, false>), dim3(Mrows / 64, 8), dim3(256), 0, stream,
                     x, W_in, b_in, h, Mrows, 512, 64);
  hipLaunchKernelGGL(add_pe, dim3(8192), dim3(256), 0, stream, h, hb, pe);

  for (int l = 0; l < 3; ++l) {
    hipLaunchKernelGGL((gemm_bf16<false, false>), dim3(128, 12), dim3(256), 0, stream,
                       hb, qkv_wb + (size_t)l * 786432, qkv_b + l * 1536, qkvf,
                       Mrows, 1536, 512);
    hipLaunchKernelGGL(flash_attn, dim3(8, 8, 32), dim3(256), 0, stream, qkvf, ctxb);
    hipLaunchKernelGGL((gemm_bf16<false, false>), dim3(128, 4), dim3(256), 0, stream,
                       ctxb, out_wb + (size_t)l * 262144, out_b + l * 512, bufC,
                       Mrows, 512, 512);
    hipLaunchKernelGGL(ln_fused, dim3(Mrows), dim3(256), 0, stream,
                       h, hb, bufC, ln1_g + l * 512, ln1_b + l * 512);
    hipLaunchKernelGGL((gemm_bf16<true, true>), dim3(128, 16), dim3(256), 0, stream,
                       hb, ff1_wb + (size_t)l * 1048576, ff1_b + l * 2048, midb,
                       Mrows, 2048, 512);
    hipLaunchKernelGGL((gemm_bf16<false, false>), dim3(128, 4), dim3(256), 0, stream,
                       midb, ff2_wb + (size_t)l * 1048576, ff2_b + l * 512, bufC,
                       Mrows, 512, 2048);
    hipLaunchKernelGGL(ln_fused, dim3(Mrows), dim3(256), 0, stream,
                       h, hb, bufC, ln2_g + l * 512, ln2_b + l * 512);
  }

  // ---- memory attention head
  hipLaunchKernelGGL((gemm_bf16<false, false>), dim3(128, 8), dim3(256), 0, stream,
                     hb, mem_b, (const float*)nullptr, attn, Mrows, 1024, 512);
  hipLaunchKernelGGL(softmax1024, dim3(Mrows), dim3(256), 0, stream, attn);
  hipLaunchKernelGGL(cvt_bf16, dim3(16384), dim3(256), 0, stream, attn, attnb, 4194304);
  hipLaunchKernelGGL((gemm_bf16<false, true>), dim3(128, 4), dim3(256), 0, stream,
                     attnb, memT_b, (const float*)nullptr, updb, Mrows, 512, 1024);
  hipLaunchKernelGGL(cat_bf16, dim3(8192), dim3(256), 0, stream, hb, updb, catb);
  hipLaunchKernelGGL((gemm_bf16<true, false>), dim3(128, 4), dim3(256), 0, stream,
                     catb, fc1_wb, fc1_b, bufC, Mrows, 512, 1024);
  hipLaunchKernelGGL((gemm64<true, false>), dim3(Mrows / 64, 1), dim3(256), 0, stream,
                     bufC, fc2_w, fc2_b, t_out, Mrows, 64, 512);

  // ---- GCN branch (f32, small)
  hipLaunchKernelGGL(fmean_kernel, dim3(32), dim3(64), 0, stream, x, fn);
  hipLaunchKernelGGL(graph_kernel, dim3(32), dim3(64), 0, stream, fn, An);
  float* xt = u1f;
  float* t1 = u1f + 1048576;
  float* h1 = u1f + 2097152;
  float* t2 = u1f + 3145728;
  hipLaunchKernelGGL(transpose_x, dim3(4096), dim3(256), 0, stream, x, xt);
  hipLaunchKernelGGL((gemm64<true, false>), dim3(2048 / 64, 8), dim3(256), 0, stream,
                     xt, gc1_w, gc1_b, t1, 2048, 512, 512);
  hipLaunchKernelGGL((bmm_an<true, false>), dim3(8, 32), dim3(256), 0, stream, An, t1, h1);
  hipLaunchKernelGGL((gemm64<true, false>), dim3(2048 / 64, 8), dim3(256), 0, stream,
                     h1, gc2_w, gc2_b, t2, 2048, 512, 512);
  hipLaunchKernelGGL((bmm_an<false, true>), dim3(8, 32), dim3(256), 0, stream, An, t2, g_out);
}

// Round 3
// 1111.527 us; speedup vs baseline: 6.2729x; 1.7352x over previous
//
#include <hip/hip_runtime.h>
#include <hip/hip_bf16.h>
#include <math.h>

// METG forward. Round 3: attention -> bf16 MFMA flash kernel (S^T/O^T swapped
// operands, lane-local softmax). Big GEMMs bf16 MFMA (round 2). LN/GCN f32.
// Shapes: B=32 S=512 F_IN=64 D=512 DFF=2048 MEM=1024 L=3 H=8 DH=64

namespace {

typedef unsigned short ushort_t;
using bf16x8 = __attribute__((ext_vector_type(8))) __bf16;
using f32x4 = __attribute__((ext_vector_type(4))) float;
using ushort8 = __attribute__((ext_vector_type(8))) unsigned short;

constexpr int Mrows = 32 * 512;  // 16384

__device__ __forceinline__ unsigned short f2bf(float f) {
  unsigned int u = __builtin_bit_cast(unsigned int, f);
  u += 0x7fffu + ((u >> 16) & 1u);
  return (unsigned short)(u >> 16);
}

__device__ __forceinline__ void g2lds16(const void* g, void* l) {
  __builtin_amdgcn_global_load_lds(
      (const __attribute__((address_space(1))) unsigned int*)g,
      (__attribute__((address_space(3))) unsigned int*)l, 16, 0, 0);
}

// ---------------- bf16 MFMA GEMM: C[M,N] = A[M,K] @ B[N,K]^T (+bias, opt relu)
template <bool RELU, bool BF16OUT>
__global__ __launch_bounds__(256) void gemm_bf16(const ushort_t* __restrict__ A,
                                                 const ushort_t* __restrict__ B,
                                                 const float* __restrict__ bias,
                                                 void* __restrict__ Cv,
                                                 int M, int N, int K) {
  __shared__ __align__(16) ushort_t As[128 * 64];
  __shared__ __align__(16) ushort_t Bs[128 * 64];
  const int t = threadIdx.x;
  const int w = t >> 6, l = t & 63;
  const int m0 = blockIdx.x << 7, n0 = blockIdx.y << 7;
  const int srow = w * 32 + (l >> 3);
  const int scol = ((l & 7) ^ (l >> 3)) << 3;
  const ushort_t* agp = A + (size_t)(m0 + srow) * K + scol;
  const ushort_t* bgp = B + (size_t)(n0 + srow) * K + scol;
  ushort_t* alds = &As[(w * 32) * 64];
  ushort_t* blds = &Bs[(w * 32) * 64];
  const int wr = w >> 1, wc = w & 1;
  const int lr = l & 15, g = l >> 4;
  const int sw = (l & 7) << 4;
  f32x4 acc[4][4] = {};
  for (int kt = 0; kt < K; kt += 64) {
    __syncthreads();
#pragma unroll
    for (int i = 0; i < 4; ++i) {
      g2lds16(agp + (size_t)(i * 8) * K + kt, alds + i * 8 * 64);
      g2lds16(bgp + (size_t)(i * 8) * K + kt, blds + i * 8 * 64);
    }
    __syncthreads();
#pragma unroll
    for (int ki = 0; ki < 2; ++ki) {
      bf16x8 af[4], bf[4];
      const int kb = (ki * 64 + g * 16) ^ sw;
#pragma unroll
      for (int mi = 0; mi < 4; ++mi)
        af[mi] = *(const bf16x8*)((const char*)As + (wr * 64 + mi * 16 + lr) * 128 + kb);
#pragma unroll
      for (int ni = 0; ni < 4; ++ni)
        bf[ni] = *(const bf16x8*)((const char*)Bs + (wc * 64 + ni * 16 + lr) * 128 + kb);
#pragma unroll
      for (int mi = 0; mi < 4; ++mi)
#pragma unroll
        for (int ni = 0; ni < 4; ++ni)
          acc[mi][ni] = __builtin_amdgcn_mfma_f32_16x16x32_bf16(af[mi], bf[ni],
                                                                acc[mi][ni], 0, 0, 0);
    }
  }
  float bb[4];
#pragma unroll
  for (int ni = 0; ni < 4; ++ni)
    bb[ni] = bias ? bias[n0 + wc * 64 + ni * 16 + lr] : 0.f;
  const int crow0 = m0 + wr * 64 + g * 4;
  const int ccol0 = n0 + wc * 64 + lr;
  if (!BF16OUT) {
    float* Cf = (float*)Cv;
#pragma unroll
    for (int mi = 0; mi < 4; ++mi)
#pragma unroll
      for (int ni = 0; ni < 4; ++ni)
#pragma unroll
        for (int v = 0; v < 4; ++v) {
          float val = acc[mi][ni][v] + bb[ni];
          if (RELU) val = fmaxf(val, 0.f);
          Cf[(size_t)(crow0 + mi * 16 + v) * N + ccol0 + ni * 16] = val;
        }
  } else {
    ushort_t* Cb = (ushort_t*)Cv;
#pragma unroll
    for (int mi = 0; mi < 4; ++mi)
#pragma unroll
      for (int ni = 0; ni < 4; ++ni)
#pragma unroll
        for (int v = 0; v < 4; ++v) {
          float val = acc[mi][ni][v] + bb[ni];
          if (RELU) val = fmaxf(val, 0.f);
          Cb[(size_t)(crow0 + mi * 16 + v) * N + ccol0 + ni * 16] = f2bf(val);
        }
  }
}

// ---------------- bf16 MFMA flash attention
// Grid (qb=8, head=8, batch=32), 256 thr = 4 waves; wave w owns q rows w*16..+15.
// S^T = mfma(K, Q): lane owns q-col (l&15); k rows = mi*16 + (l>>4)*4 + v.
// O^T = mfma(VT, P): lane owns q-col; dh rows = mi*16 + (l>>4)*4 + v.
__global__ __launch_bounds__(256) void flash_attn_mfma(const ushort_t* __restrict__ qkvb,
                                                       ushort_t* __restrict__ ctxb) {
  __shared__ __align__(16) ushort_t Qs[64 * 64];
  __shared__ __align__(16) ushort_t Ks[64 * 64];
  __shared__ __align__(16) ushort_t VT[64 * 64];
  __shared__ __align__(16) ushort_t Ps[64 * 64];
  const int qb = blockIdx.x, hh = blockIdx.y, b = blockIdx.z;
  const int t = threadIdx.x, w = t >> 6, l = t & 63;
  const int g = l >> 4, lr = l & 15, l7 = l & 7;
  const ushort_t* qkv0 = qkvb + (size_t)b * 512 * 1536 + hh * 64;
  // stage Q once (rows qb*64 + w*16 + i*8 + (l>>3)), pre-swizzled source
  {
    const int r8 = l >> 3;
    const int gcol = (l7 ^ r8) << 3;
#pragma unroll
    for (int i = 0; i < 2; ++i) {
      const int row = w * 16 + i * 8 + r8;
      g2lds16(qkv0 + (size_t)(qb * 64 + row) * 1536 + gcol, &Qs[(w * 16 + i * 8) * 64]);
    }
  }
  float mst = -INFINITY, lst = 0.f;
  f32x4 oacc[4] = {};
  const int vk0 = (t & 31) * 2;    // V staging: k pair base
  const int vdh0 = (t >> 5) * 8;   // V staging: dh group
  for (int kt = 0; kt < 8; ++kt) {
    __syncthreads();
    // stage K tile
    {
      const int r8 = l >> 3;
      const int gcol = (l7 ^ r8) << 3;
#pragma unroll
      for (int i = 0; i < 2; ++i) {
        const int row = w * 16 + i * 8 + r8;
        g2lds16(qkv0 + 512 + (size_t)(kt * 64 + row) * 1536 + gcol,
                &Ks[(w * 16 + i * 8) * 64]);
      }
    }
    // stage V transposed: VT[dh][k], packed pairs along k, row-XOR swizzle
    {
      const ushort_t* vp = qkv0 + 1024 + (size_t)(kt * 64 + vk0) * 1536 + vdh0;
      ushort8 v0 = *(const ushort8*)vp;
      ushort8 v1 = *(const ushort8*)(vp + 1536);
      const int slotbase = vk0 >> 3;
      const int inb = (vk0 & 7) * 2;
#pragma unroll
      for (int e = 0; e < 8; ++e) {
        const int dh = vdh0 + e;
        unsigned int word = (unsigned int)v0[e] | ((unsigned int)v1[e] << 16);
        *(unsigned int*)((char*)VT + dh * 128 + (((slotbase ^ (dh & 7)) << 4) + inb)) = word;
      }
    }
    __syncthreads();
    // S^T = K @ Q^T
    f32x4 sacc[4] = {};
#pragma unroll
    for (int ki = 0; ki < 2; ++ki) {
      const int sb = ((ki * 4 + g) ^ l7) << 4;
      bf16x8 qf = *(const bf16x8*)((const char*)Qs + (w * 16 + lr) * 128 + sb);
#pragma unroll
      for (int mi = 0; mi < 4; ++mi) {
        bf16x8 kf = *(const bf16x8*)((const char*)Ks + (mi * 16 + lr) * 128 + sb);
        sacc[mi] = __builtin_amdgcn_mfma_f32_16x16x32_bf16(kf, qf, sacc[mi], 0, 0, 0);
      }
    }
    // online softmax for q-col (l&15); cross-lane over xor 16,32
    float p[4][4];
    float cmax = -INFINITY;
#pragma unroll
    for (int mi = 0; mi < 4; ++mi)
#pragma unroll
      for (int v = 0; v < 4; ++v) {
        p[mi][v] = sacc[mi][v] * 0.125f;
        cmax = fmaxf(cmax, p[mi][v]);
      }
    cmax = fmaxf(cmax, __shfl_xor(cmax, 16));
    cmax = fmaxf(cmax, __shfl_xor(cmax, 32));
    const float mnew = fmaxf(mst, cmax);
    const float al = __expf(mst - mnew);
    float csum = 0.f;
#pragma unroll
    for (int mi = 0; mi < 4; ++mi)
#pragma unroll
      for (int v = 0; v < 4; ++v) {
        p[mi][v] = __expf(p[mi][v] - mnew);
        csum += p[mi][v];
      }
    csum += __shfl_xor(csum, 16);
    csum += __shfl_xor(csum, 32);
    lst = lst * al + csum;
    mst = mnew;
#pragma unroll
    for (int mi = 0; mi < 4; ++mi) oacc[mi] *= al;
    // write P rows (wave-local, bf16, packed pairs, same swizzle)
    {
      char* pbase = (char*)Ps + (w * 16 + lr) * 128;
#pragma unroll
      for (int mi = 0; mi < 4; ++mi)
#pragma unroll
        for (int vp2 = 0; vp2 < 2; ++vp2) {
          const int klo = mi * 16 + g * 4 + vp2 * 2;
          unsigned int word = (unsigned int)f2bf(p[mi][vp2 * 2]) |
                              ((unsigned int)f2bf(p[mi][vp2 * 2 + 1]) << 16);
          *(unsigned int*)(pbase + (((klo >> 3) ^ l7) << 4) + (klo & 7) * 2) = word;
        }
    }
    // O^T += VT @ P^T
#pragma unroll
    for (int ki = 0; ki < 2; ++ki) {
      const int sb = ((ki * 4 + g) ^ l7) << 4;
      bf16x8 pf = *(const bf16x8*)((const char*)Ps + (w * 16 + lr) * 128 + sb);
#pragma unroll
      for (int mi = 0; mi < 4; ++mi) {
        bf16x8 vf = *(const bf16x8*)((const char*)VT + (mi * 16 + lr) * 128 + sb);
        oacc[mi] = __builtin_amdgcn_mfma_f32_16x16x32_bf16(vf, pf, oacc[mi], 0, 0, 0);
      }
    }
  }
  const float inv = 1.f / lst;
  ushort_t* op = ctxb + (size_t)(b * 512 + qb * 64 + w * 16 + lr) * 512 + hh * 64;
#pragma unroll
  for (int mi = 0; mi < 4; ++mi)
#pragma unroll
    for (int vp2 = 0; vp2 < 2; ++vp2) {
      const int dh = mi * 16 + g * 4 + vp2 * 2;
      unsigned int word = (unsigned int)f2bf(oacc[mi][vp2 * 2] * inv) |
                          ((unsigned int)f2bf(oacc[mi][vp2 * 2 + 1] * inv) << 16);
      *(unsigned int*)(op + dh) = word;
    }
}

// ---------------- f32 fallback GEMM (small ops)
#define OUTER16(ACC, A4, B4) do { \
  ACC[0][0] += (A4).x*(B4).x; ACC[0][1] += (A4).x*(B4).y; ACC[0][2] += (A4).x*(B4).z; ACC[0][3] += (A4).x*(B4).w; \
  ACC[1][0] += (A4).y*(B4).x; ACC[1][1] += (A4).y*(B4).y; ACC[1][2] += (A4).y*(B4).z; ACC[1][3] += (A4).y*(B4).w; \
  ACC[2][0] += (A4).z*(B4).x; ACC[2][1] += (A4).z*(B4).y; ACC[2][2] += (A4).z*(B4).z; ACC[2][3] += (A4).z*(B4).w; \
  ACC[3][0] += (A4).w*(B4).x; ACC[3][1] += (A4).w*(B4).y; ACC[3][2] += (A4).w*(B4).z; ACC[3][3] += (A4).w*(B4).w; \
} while (0)

template <bool BT, bool RELU>
__global__ __launch_bounds__(256) void gemm64(const float* __restrict__ A,
                                              const float* __restrict__ Bm,
                                              const float* __restrict__ bias,
                                              float* __restrict__ C,
                                              int M, int N, int K) {
  __shared__ float As[16][68];
  __shared__ float Bs[16][68];
  const int t = threadIdx.x;
  const int m0 = blockIdx.x << 6;
  const int n0 = blockIdx.y << 6;
  const int r0 = (t >> 4) << 2;
  const int c0 = (t & 15) << 2;
  const int lm = t >> 2;
  const int lk4 = (t & 3) << 2;
  const int lkk = t >> 4;
  const int ln = (t & 15) << 2;
  float acc[4][4] = {{0.f, 0.f, 0.f, 0.f}, {0.f, 0.f, 0.f, 0.f},
                     {0.f, 0.f, 0.f, 0.f}, {0.f, 0.f, 0.f, 0.f}};
  for (int kt = 0; kt < K; kt += 16) {
    __syncthreads();
    float4 av = *reinterpret_cast<const float4*>(A + (size_t)(m0 + lm) * K + kt + lk4);
    As[lk4 + 0][lm] = av.x; As[lk4 + 1][lm] = av.y;
    As[lk4 + 2][lm] = av.z; As[lk4 + 3][lm] = av.w;
    if (BT) {
      float4 bv = *reinterpret_cast<const float4*>(Bm + (size_t)(n0 + lm) * K + kt + lk4);
      Bs[lk4 + 0][lm] = bv.x; Bs[lk4 + 1][lm] = bv.y;
      Bs[lk4 + 2][lm] = bv.z; Bs[lk4 + 3][lm] = bv.w;
    } else {
      float4 bv = *reinterpret_cast<const float4*>(Bm + (size_t)(kt + lkk) * N + n0 + ln);
      *reinterpret_cast<float4*>(&Bs[lkk][ln]) = bv;
    }
    __syncthreads();
#pragma unroll
    for (int k = 0; k < 16; ++k) {
      float4 a4 = *reinterpret_cast<const float4*>(&As[k][r0]);
      float4 b4 = *reinterpret_cast<const float4*>(&Bs[k][c0]);
      OUTER16(acc, a4, b4);
    }
  }
  float bb0 = 0.f, bb1 = 0.f, bb2 = 0.f, bb3 = 0.f;
  if (bias) {
    bb0 = bias[n0 + c0 + 0]; bb1 = bias[n0 + c0 + 1];
    bb2 = bias[n0 + c0 + 2]; bb3 = bias[n0 + c0 + 3];
  }
#pragma unroll
  for (int i = 0; i < 4; ++i) {
    float4 o;
    o.x = acc[i][0] + bb0; o.y = acc[i][1] + bb1;
    o.z = acc[i][2] + bb2; o.w = acc[i][3] + bb3;
    if (RELU) {
      o.x = fmaxf(o.x, 0.f); o.y = fmaxf(o.y, 0.f);
      o.z = fmaxf(o.z, 0.f); o.w = fmaxf(o.w, 0.f);
    }
    *reinterpret_cast<float4*>(C + (size_t)(m0 + r0 + i) * N + n0 + c0) = o;
  }
}

__device__ __forceinline__ float bsum256(float v, float* red) {
#pragma unroll
  for (int off = 32; off; off >>= 1) v += __shfl_down(v, off);
  __syncthreads();
  if ((threadIdx.x & 63) == 0) red[threadIdx.x >> 6] = v;
  __syncthreads();
  return red[0] + red[1] + red[2] + red[3];
}

__device__ __forceinline__ float bmax256(float v, float* red) {
#pragma unroll
  for (int off = 32; off; off >>= 1) v = fmaxf(v, __shfl_down(v, off));
  __syncthreads();
  if ((threadIdx.x & 63) == 0) red[threadIdx.x >> 6] = v;
  __syncthreads();
  return fmaxf(fmaxf(red[0], red[1]), fmaxf(red[2], red[3]));
}

// h = LN(h + res); writes f32 h and bf16 hb.
__global__ __launch_bounds__(256) void ln_fused(float* __restrict__ h,
                                                ushort_t* __restrict__ hb,
                                                const float* __restrict__ res,
                                                const float* __restrict__ g,
                                                const float* __restrict__ bt) {
  __shared__ float red[4];
  const size_t row = blockIdx.x;
  float* hp = h + row * 512;
  ushort_t* hbp = hb + row * 512;
  const float* rp = res + row * 512;
  const int t = threadIdx.x;
  float x0 = hp[t] + rp[t];
  float x1 = hp[t + 256] + rp[t + 256];
  float mean = bsum256(x0 + x1, red) * (1.f / 512.f);
  float d0 = x0 - mean, d1 = x1 - mean;
  float var = bsum256(d0 * d0 + d1 * d1, red) * (1.f / 512.f);
  float rstd = rsqrtf(var + 1e-5f);
  float y0 = d0 * rstd * g[t] + bt[t];
  float y1 = d1 * rstd * g[t + 256] + bt[t + 256];
  hp[t] = y0; hp[t + 256] = y1;
  hbp[t] = f2bf(y0); hbp[t + 256] = f2bf(y1);
}

__global__ __launch_bounds__(256) void softmax1024(float* __restrict__ p) {
  __shared__ float red[4];
  float4* rp = reinterpret_cast<float4*>(p + (size_t)blockIdx.x * 1024);
  const int t = threadIdx.x;
  float4 v = rp[t];
  float mx = bmax256(fmaxf(fmaxf(v.x, v.y), fmaxf(v.z, v.w)), red);
  float e0 = expf(v.x - mx), e1 = expf(v.y - mx), e2 = expf(v.z - mx), e3 = expf(v.w - mx);
  float sm = bsum256(e0 + e1 + e2 + e3, red);
  float inv = 1.f / sm;
  rp[t] = make_float4(e0 * inv, e1 * inv, e2 * inv, e3 * inv);
}

__global__ void pe_kernel(float* __restrict__ pe) {
  const int s = blockIdx.x, i = threadIdx.x;
  double div = exp((double)(2 * i) * (-log(10000.0) / 512.0));
  double a = (double)s * div;
  pe[s * 512 + 2 * i] = (float)sin(a);
  pe[s * 512 + 2 * i + 1] = (float)cos(a);
}

__global__ __launch_bounds__(256) void add_pe(float* __restrict__ h,
                                              ushort_t* __restrict__ hb,
                                              const float* __restrict__ pe) {
  const size_t g = (size_t)blockIdx.x * 256 + threadIdx.x;
  const int c4 = (int)(g & 127);
  const size_t mrow = g >> 7;
  const int s = (int)(mrow & 511);
  float4 v = reinterpret_cast<float4*>(h)[g];
  float4 p = reinterpret_cast<const float4*>(pe)[(size_t)s * 128 + c4];
  v.x += p.x; v.y += p.y; v.z += p.z; v.w += p.w;
  reinterpret_cast<float4*>(h)[g] = v;
  ushort4 o;
  o.x = f2bf(v.x); o.y = f2bf(v.y); o.z = f2bf(v.z); o.w = f2bf(v.w);
  reinterpret_cast<ushort4*>(hb)[g] = o;
}

__global__ __launch_bounds__(256) void cvt_bf16(const float* __restrict__ in,
                                                ushort_t* __restrict__ out, int n4) {
  const int g = blockIdx.x * 256 + threadIdx.x;
  if (g >= n4) return;
  float4 v = reinterpret_cast<const float4*>(in)[g];
  ushort4 o;
  o.x = f2bf(v.x); o.y = f2bf(v.y); o.z = f2bf(v.z); o.w = f2bf(v.w);
  reinterpret_cast<ushort4*>(out)[g] = o;
}

// memory [1024,512] f32 -> memT bf16 [512,1024]
__global__ __launch_bounds__(256) void transpose_cvt(const float* __restrict__ in,
                                                     ushort_t* __restrict__ out) {
  const int g = blockIdx.x * 256 + threadIdx.x;
  const int r = g >> 9, c = g & 511;
  out[(size_t)c * 1024 + r] = f2bf(in[g]);
}

__global__ __launch_bounds__(256) void cat_bf16(const ushort_t* __restrict__ hb,
                                                const ushort_t* __restrict__ ub,
                                                ushort_t* __restrict__ cb) {
  const size_t g = (size_t)blockIdx.x * 256 + threadIdx.x;
  const size_t mrow = g >> 7;
  const int c = (int)(g & 127);
  uint4 v = (c < 64) ? reinterpret_cast<const uint4*>(hb)[mrow * 64 + c]
                     : reinterpret_cast<const uint4*>(ub)[mrow * 64 + (c - 64)];
  reinterpret_cast<uint4*>(cb)[g] = v;
}

__global__ __launch_bounds__(256) void transpose_x(const float* __restrict__ x,
                                                   float* __restrict__ xt) {
  const size_t g = (size_t)blockIdx.x * 256 + threadIdx.x;
  const int s = (int)(g & 511);
  const int f = (int)((g >> 9) & 63);
  const int b = (int)(g >> 15);
  xt[g] = x[((size_t)b * 512 + s) * 64 + f];
}

__global__ void fmean_kernel(const float* __restrict__ x, float* __restrict__ fn) {
  const int b = blockIdx.x, f = threadIdx.x;
  float s = 0.f;
  const float* xp = x + (size_t)b * 512 * 64 + f;
  for (int i = 0; i < 512; ++i) s += xp[(size_t)i * 64];
  s *= (1.f / 512.f);
  float ss = s * s;
#pragma unroll
  for (int off = 32; off; off >>= 1) ss += __shfl_down(ss, off);
  ss = __shfl(ss, 0);
  float n = fmaxf(sqrtf(ss), 1e-12f);
  fn[b * 64 + f] = s / n;
}

__global__ void graph_kernel(const float* __restrict__ fn, float* __restrict__ An) {
  __shared__ float fv[64];
  __shared__ float Am[64][65];
  const int b = blockIdx.x, i = threadIdx.x;
  fv[i] = fn[b * 64 + i];
#pragma unroll
  for (int j = 0; j < 64; ++j) Am[i][j] = 0.f;
  __syncthreads();
  const float fi = fv[i];
  unsigned long long mask = 0ull;
  int sel[4];
  for (int t4 = 0; t4 < 4; ++t4) {
    float best = -INFINITY;
    int bi = 0;
    for (int j = 0; j < 64; ++j) {
      if (mask & (1ull << j)) continue;
      float v = fi * fv[j];
      if (v > best) { best = v; bi = j; }
    }
    mask |= (1ull << bi);
    sel[t4] = bi;
  }
  Am[i][sel[1]] = 1.f; Am[i][sel[2]] = 1.f; Am[i][sel[3]] = 1.f;
  __syncthreads();
  float deg = 0.f;
  for (int j = 0; j < 64; ++j) deg += (j == i) ? 1.f : fmaxf(Am[i][j], Am[j][i]);
  const float inv = 1.f / deg;
  float* out = An + ((size_t)b * 64 + i) * 64;
  for (int j = 0; j < 64; ++j)
    out[j] = ((j == i) ? 1.f : fmaxf(Am[i][j], Am[j][i])) * inv;
}

template <bool RELU, bool STORE_T>
__global__ __launch_bounds__(256) void bmm_an(const float* __restrict__ An,
                                              const float* __restrict__ X,
                                              float* __restrict__ Y) {
  __shared__ float Ag[64][68];
  __shared__ float Xs[64][68];
  const int nc = blockIdx.x << 6;
  const int b = blockIdx.y;
  const int t = threadIdx.x;
  {
    const int i = t >> 2, g0 = (t & 3) << 4;
    const float* ap = An + ((size_t)b * 64 + i) * 64 + g0;
#pragma unroll
    for (int j = 0; j < 16; ++j) Ag[g0 + j][i] = ap[j];
  }
  {
    const int g = t >> 2, n4 = (t & 3) << 4;
    const float* xp = X + ((size_t)b * 64 + g) * 512 + nc + n4;
#pragma unroll
    for (int j = 0; j < 4; ++j)
      *reinterpret_cast<float4*>(&Xs[g][n4 + 4 * j]) =
          *reinterpret_cast<const float4*>(xp + 4 * j);
  }
  __syncthreads();
  const int r0 = (t >> 4) << 2, c0 = (t & 15) << 2;
  float acc[4][4] = {{0.f, 0.f, 0.f, 0.f}, {0.f, 0.f, 0.f, 0.f},
                     {0.f, 0.f, 0.f, 0.f}, {0.f, 0.f, 0.f, 0.f}};
#pragma unroll 8
  for (int g = 0; g < 64; ++g) {
    float4 a4 = *reinterpret_cast<const float4*>(&Ag[g][r0]);
    float4 x4 = *reinterpret_cast<const float4*>(&Xs[g][c0]);
    OUTER16(acc, a4, x4);
  }
  if (!STORE_T) {
#pragma unroll
    for (int i = 0; i < 4; ++i) {
      float4 o = make_float4(acc[i][0], acc[i][1], acc[i][2], acc[i][3]);
      if (RELU) {
        o.x = fmaxf(o.x, 0.f); o.y = fmaxf(o.y, 0.f);
        o.z = fmaxf(o.z, 0.f); o.w = fmaxf(o.w, 0.f);
      }
      *reinterpret_cast<float4*>(Y + ((size_t)b * 64 + r0 + i) * 512 + nc + c0) = o;
    }
  } else {
#pragma unroll
    for (int j = 0; j < 4; ++j) {
      float4 o = make_float4(acc[0][j], acc[1][j], acc[2][j], acc[3][j]);
      *reinterpret_cast<float4*>(Y + ((size_t)b * 512 + nc + c0 + j) * 64 + r0) = o;
    }
  }
}

}  // namespace

extern "C" void kernel_launch(void* const* d_in, const int* in_sizes, int n_in,
                              void* d_out, int out_size, void* d_ws, size_t ws_size,
                              hipStream_t stream) {
  const float* x     = (const float*)d_in[0];
  const float* W_in  = (const float*)d_in[1];
  const float* b_in  = (const float*)d_in[2];
  const float* qkv_w = (const float*)d_in[3];
  const float* qkv_b = (const float*)d_in[4];
  const float* out_w = (const float*)d_in[5];
  const float* out_b = (const float*)d_in[6];
  const float* ln1_g = (const float*)d_in[7];
  const float* ln1_b = (const float*)d_in[8];
  const float* ln2_g = (const float*)d_in[9];
  const float* ln2_b = (const float*)d_in[10];
  const float* ff1_w = (const float*)d_in[11];
  const float* ff1_b = (const float*)d_in[12];
  const float* ff2_w = (const float*)d_in[13];
  const float* ff2_b = (const float*)d_in[14];
  const float* memw  = (const float*)d_in[15];
  const float* fc1_w = (const float*)d_in[16];
  const float* fc1_b = (const float*)d_in[17];
  const float* fc2_w = (const float*)d_in[18];
  const float* fc2_b = (const float*)d_in[19];
  const float* gc1_w = (const float*)d_in[20];
  const float* gc1_b = (const float*)d_in[21];
  const float* gc2_w = (const float*)d_in[22];
  const float* gc2_b = (const float*)d_in[23];

  char* wsb = (char*)d_ws;
  float*    h      = (float*)(wsb + 0);               // 32MB
  ushort_t* hb     = (ushort_t*)(wsb + 33554432);     // 16MB
  char*     U1     = wsb + 50331648;                  // 96MB shared region
  ushort_t* ctxb   = (ushort_t*)(wsb + 150994944);    // 16MB
  float*    bufC   = (float*)(wsb + 167772160);       // 32MB
  float*    pe     = (float*)(wsb + 201326592);       // 1MB
  ushort_t* qkv_wb = (ushort_t*)(wsb + 202375168);    // 4.5MB
  ushort_t* out_wb = (ushort_t*)(wsb + 207093760);    // 1.5MB
  ushort_t* ff1_wb = (ushort_t*)(wsb + 208666624);    // 6MB
  ushort_t* ff2_wb = (ushort_t*)(wsb + 214958080);    // 6MB
  ushort_t* mem_b  = (ushort_t*)(wsb + 221249536);    // 1MB
  ushort_t* memT_b = (ushort_t*)(wsb + 222298112);    // 1MB
  ushort_t* fc1_wb = (ushort_t*)(wsb + 223346688);    // 1MB
  float*    fn     = (float*)(wsb + 224395264);       // 8KB
  float*    An     = (float*)(wsb + 224403456);       // 512KB

  // U1 overlays (sequentially dead):
  ushort_t* qkvb  = (ushort_t*)U1;                     // 48MB (per-layer qkv, bf16)
  ushort_t* midb  = (ushort_t*)U1;                     // 64MB (ff1 out)
  ushort_t* attnb = (ushort_t*)U1;                     // 32MB
  ushort_t* catb  = (ushort_t*)(U1 + 33554432);        // 32MB
  ushort_t* updb  = (ushort_t*)(U1 + 67108864);        // 16MB
  float*    u1f   = (float*)U1;                        // GCN scratch

  float* t_out = (float*)d_out;
  float* g_out = t_out + 1048576;
  float* attn  = g_out + 1048576;

  // ---- weight conversions
  hipLaunchKernelGGL(cvt_bf16, dim3(2304), dim3(256), 0, stream, qkv_w, qkv_wb, 589824);
  hipLaunchKernelGGL(cvt_bf16, dim3(768), dim3(256), 0, stream, out_w, out_wb, 196608);
  hipLaunchKernelGGL(cvt_bf16, dim3(3072), dim3(256), 0, stream, ff1_w, ff1_wb, 786432);
  hipLaunchKernelGGL(cvt_bf16, dim3(3072), dim3(256), 0, stream, ff2_w, ff2_wb, 786432);
  hipLaunchKernelGGL(cvt_bf16, dim3(512), dim3(256), 0, stream, memw, mem_b, 131072);
  hipLaunchKernelGGL(cvt_bf16, dim3(512), dim3(256), 0, stream, fc1_w, fc1_wb, 131072);
  hipLaunchKernelGGL(transpose_cvt, dim3(2048), dim3(256), 0, stream, memw, memT_b);
  hipLaunchKernelGGL(pe_kernel, dim3(512), dim3(256), 0, stream, pe);

  // ---- input projection (f32) + positional encoding
  hipLaunchKernelGGL((gemm64<true, false>), dim3(Mrows / 64, 8), dim3(256), 0, stream,
                     x, W_in, b_in, h, Mrows, 512, 64);
  hipLaunchKernelGGL(add_pe, dim3(8192), dim3(256), 0, stream, h, hb, pe);

  for (int l = 0; l < 3; ++l) {
    hipLaunchKernelGGL((gemm_bf16<false, true>), dim3(128, 12), dim3(256), 0, stream,
                       hb, qkv_wb + (size_t)l * 786432, qkv_b + l * 1536, qkvb,
                       Mrows, 1536, 512);
    hipLaunchKernelGGL(flash_attn_mfma, dim3(8, 8, 32), dim3(256), 0, stream, qkvb, ctxb);
    hipLaunchKernelGGL((gemm_bf16<false, false>), dim3(128, 4), dim3(256), 0, stream,
                       ctxb, out_wb + (size_t)l * 262144, out_b + l * 512, bufC,
                       Mrows, 512, 512);
    hipLaunchKernelGGL(ln_fused, dim3(Mrows), dim3(256), 0, stream,
                       h, hb, bufC, ln1_g + l * 512, ln1_b + l * 512);
    hipLaunchKernelGGL((gemm_bf16<true, true>), dim3(128, 16), dim3(256), 0, stream,
                       hb, ff1_wb + (size_t)l * 1048576, ff1_b + l * 2048, midb,
                       Mrows, 2048, 512);
    hipLaunchKernelGGL((gemm_bf16<false, false>), dim3(128, 4), dim3(256), 0, stream,
                       midb, ff2_wb + (size_t)l * 1048576, ff2_b + l * 512, bufC,
                       Mrows, 512, 2048);
    hipLaunchKernelGGL(ln_fused, dim3(Mrows), dim3(256), 0, stream,
                       h, hb, bufC, ln2_g + l * 512, ln2_b + l * 512);
  }

  // ---- memory attention head
  hipLaunchKernelGGL((gemm_bf16<false, false>), dim3(128, 8), dim3(256), 0, stream,
                     hb, mem_b, (const float*)nullptr, attn, Mrows, 1024, 512);
  hipLaunchKernelGGL(softmax1024, dim3(Mrows), dim3(256), 0, stream, attn);
  hipLaunchKernelGGL(cvt_bf16, dim3(16384), dim3(256), 0, stream, attn, attnb, 4194304);
  hipLaunchKernelGGL((gemm_bf16<false, true>), dim3(128, 4), dim3(256), 0, stream,
                     attnb, memT_b, (const float*)nullptr, updb, Mrows, 512, 1024);
  hipLaunchKernelGGL(cat_bf16, dim3(8192), dim3(256), 0, stream, hb, updb, catb);
  hipLaunchKernelGGL((gemm_bf16<true, false>), dim3(128, 4), dim3(256), 0, stream,
                     catb, fc1_wb, fc1_b, bufC, Mrows, 512, 1024);
  hipLaunchKernelGGL((gemm64<true, false>), dim3(Mrows / 64, 1), dim3(256), 0, stream,
                     bufC, fc2_w, fc2_b, t_out, Mrows, 64, 512);

  // ---- GCN branch (f32, small)
  hipLaunchKernelGGL(fmean_kernel, dim3(32), dim3(64), 0, stream, x, fn);
  hipLaunchKernelGGL(graph_kernel, dim3(32), dim3(64), 0, stream, fn, An);
  float* xt = u1f;
  float* t1 = u1f + 1048576;
  float* h1 = u1f + 2097152;
  float* t2 = u1f + 3145728;
  hipLaunchKernelGGL(transpose_x, dim3(4096), dim3(256), 0, stream, x, xt);
  hipLaunchKernelGGL((gemm64<true, false>), dim3(2048 / 64, 8), dim3(256), 0, stream,
                     xt, gc1_w, gc1_b, t1, 2048, 512, 512);
  hipLaunchKernelGGL((bmm_an<true, false>), dim3(8, 32), dim3(256), 0, stream, An, t1, h1);
  hipLaunchKernelGGL((gemm64<true, false>), dim3(2048 / 64, 8), dim3(256), 0, stream,
                     h1, gc2_w, gc2_b, t2, 2048, 512, 512);
  hipLaunchKernelGGL((bmm_an<false, true>), dim3(8, 32), dim3(256), 0, stream, An, t2, g_out);
}

// Round 4
// 971.695 us; speedup vs baseline: 7.1756x; 1.1439x over previous
//
#include <hip/hip_runtime.h>
#include <hip/hip_bf16.h>
#include <math.h>

// METG forward. Round 4: parallel graph/fmean/transpose, fused epilogues
// (PE in W_in GEMM, softmax+cvt, LN->cat, upd->cat via ldc), bf16 residuals,
// GCN GEMMs -> MFMA, merged weight conversions.
// Shapes: B=32 S=512 F_IN=64 D=512 DFF=2048 MEM=1024 L=3 H=8 DH=64

namespace {

typedef unsigned short ushort_t;
using bf16x8 = __attribute__((ext_vector_type(8))) __bf16;
using f32x4 = __attribute__((ext_vector_type(4))) float;
using ushort8 = __attribute__((ext_vector_type(8))) unsigned short;

constexpr int Mrows = 32 * 512;  // 16384

__device__ __forceinline__ unsigned short f2bf(float f) {
  unsigned int u = __builtin_bit_cast(unsigned int, f);
  u += 0x7fffu + ((u >> 16) & 1u);
  return (unsigned short)(u >> 16);
}
__device__ __forceinline__ float bf2f(ushort_t u) {
  unsigned int v = ((unsigned int)u) << 16;
  return __builtin_bit_cast(float, v);
}

__device__ __forceinline__ void g2lds16(const void* g, void* l) {
  __builtin_amdgcn_global_load_lds(
      (const __attribute__((address_space(1))) unsigned int*)g,
      (__attribute__((address_space(3))) unsigned int*)l, 16, 0, 0);
}

// ---------------- bf16 MFMA GEMM: C[M,N] = A[M,K](lda) @ B[N,K]^T (+bias,relu)
template <bool RELU, bool BF16OUT>
__global__ __launch_bounds__(256) void gemm_bf16(const ushort_t* __restrict__ A,
                                                 const ushort_t* __restrict__ B,
                                                 const float* __restrict__ bias,
                                                 void* __restrict__ Cv,
                                                 int M, int N, int K,
                                                 int lda, int ldc) {
  __shared__ __align__(16) ushort_t As[128 * 64];
  __shared__ __align__(16) ushort_t Bs[128 * 64];
  const int t = threadIdx.x;
  const int w = t >> 6, l = t & 63;
  const int m0 = blockIdx.x << 7, n0 = blockIdx.y << 7;
  const int srow = w * 32 + (l >> 3);
  const int scol = ((l & 7) ^ (l >> 3)) << 3;
  const ushort_t* agp = A + (size_t)(m0 + srow) * lda + scol;
  const ushort_t* bgp = B + (size_t)(n0 + srow) * K + scol;
  ushort_t* alds = &As[(w * 32) * 64];
  ushort_t* blds = &Bs[(w * 32) * 64];
  const int wr = w >> 1, wc = w & 1;
  const int lr = l & 15, g = l >> 4;
  const int sw = (l & 7) << 4;
  f32x4 acc[4][4] = {};
  for (int kt = 0; kt < K; kt += 64) {
    __syncthreads();
#pragma unroll
    for (int i = 0; i < 4; ++i) {
      g2lds16(agp + (size_t)(i * 8) * lda + kt, alds + i * 8 * 64);
      g2lds16(bgp + (size_t)(i * 8) * K + kt, blds + i * 8 * 64);
    }
    __syncthreads();
#pragma unroll
    for (int ki = 0; ki < 2; ++ki) {
      bf16x8 af[4], bf[4];
      const int kb = (ki * 64 + g * 16) ^ sw;
#pragma unroll
      for (int mi = 0; mi < 4; ++mi)
        af[mi] = *(const bf16x8*)((const char*)As + (wr * 64 + mi * 16 + lr) * 128 + kb);
#pragma unroll
      for (int ni = 0; ni < 4; ++ni)
        bf[ni] = *(const bf16x8*)((const char*)Bs + (wc * 64 + ni * 16 + lr) * 128 + kb);
#pragma unroll
      for (int mi = 0; mi < 4; ++mi)
#pragma unroll
        for (int ni = 0; ni < 4; ++ni)
          acc[mi][ni] = __builtin_amdgcn_mfma_f32_16x16x32_bf16(af[mi], bf[ni],
                                                                acc[mi][ni], 0, 0, 0);
    }
  }
  float bb[4];
#pragma unroll
  for (int ni = 0; ni < 4; ++ni)
    bb[ni] = bias ? bias[n0 + wc * 64 + ni * 16 + lr] : 0.f;
  const int crow0 = m0 + wr * 64 + g * 4;
  const int ccol0 = n0 + wc * 64 + lr;
  if (!BF16OUT) {
    float* Cf = (float*)Cv;
#pragma unroll
    for (int mi = 0; mi < 4; ++mi)
#pragma unroll
      for (int ni = 0; ni < 4; ++ni)
#pragma unroll
        for (int v = 0; v < 4; ++v) {
          float val = acc[mi][ni][v] + bb[ni];
          if (RELU) val = fmaxf(val, 0.f);
          Cf[(size_t)(crow0 + mi * 16 + v) * ldc + ccol0 + ni * 16] = val;
        }
  } else {
    ushort_t* Cb = (ushort_t*)Cv;
#pragma unroll
    for (int mi = 0; mi < 4; ++mi)
#pragma unroll
      for (int ni = 0; ni < 4; ++ni)
#pragma unroll
        for (int v = 0; v < 4; ++v) {
          float val = acc[mi][ni][v] + bb[ni];
          if (RELU) val = fmaxf(val, 0.f);
          Cb[(size_t)(crow0 + mi * 16 + v) * ldc + ccol0 + ni * 16] = f2bf(val);
        }
  }
}

// ---------------- bf16 MFMA flash attention (unchanged from round 3)
__global__ __launch_bounds__(256) void flash_attn_mfma(const ushort_t* __restrict__ qkvb,
                                                       ushort_t* __restrict__ ctxb) {
  __shared__ __align__(16) ushort_t Qs[64 * 64];
  __shared__ __align__(16) ushort_t Ks[64 * 64];
  __shared__ __align__(16) ushort_t VT[64 * 64];
  __shared__ __align__(16) ushort_t Ps[64 * 64];
  const int qb = blockIdx.x, hh = blockIdx.y, b = blockIdx.z;
  const int t = threadIdx.x, w = t >> 6, l = t & 63;
  const int g = l >> 4, lr = l & 15, l7 = l & 7;
  const ushort_t* qkv0 = qkvb + (size_t)b * 512 * 1536 + hh * 64;
  {
    const int r8 = l >> 3;
    const int gcol = (l7 ^ r8) << 3;
#pragma unroll
    for (int i = 0; i < 2; ++i) {
      const int row = w * 16 + i * 8 + r8;
      g2lds16(qkv0 + (size_t)(qb * 64 + row) * 1536 + gcol, &Qs[(w * 16 + i * 8) * 64]);
    }
  }
  float mst = -INFINITY, lst = 0.f;
  f32x4 oacc[4] = {};
  const int vk0 = (t & 31) * 2;
  const int vdh0 = (t >> 5) * 8;
  for (int kt = 0; kt < 8; ++kt) {
    __syncthreads();
    {
      const int r8 = l >> 3;
      const int gcol = (l7 ^ r8) << 3;
#pragma unroll
      for (int i = 0; i < 2; ++i) {
        const int row = w * 16 + i * 8 + r8;
        g2lds16(qkv0 + 512 + (size_t)(kt * 64 + row) * 1536 + gcol,
                &Ks[(w * 16 + i * 8) * 64]);
      }
    }
    {
      const ushort_t* vp = qkv0 + 1024 + (size_t)(kt * 64 + vk0) * 1536 + vdh0;
      ushort8 v0 = *(const ushort8*)vp;
      ushort8 v1 = *(const ushort8*)(vp + 1536);
      const int slotbase = vk0 >> 3;
      const int inb = (vk0 & 7) * 2;
#pragma unroll
      for (int e = 0; e < 8; ++e) {
        const int dh = vdh0 + e;
        unsigned int word = (unsigned int)v0[e] | ((unsigned int)v1[e] << 16);
        *(unsigned int*)((char*)VT + dh * 128 + (((slotbase ^ (dh & 7)) << 4) + inb)) = word;
      }
    }
    __syncthreads();
    f32x4 sacc[4] = {};
#pragma unroll
    for (int ki = 0; ki < 2; ++ki) {
      const int sb = ((ki * 4 + g) ^ l7) << 4;
      bf16x8 qf = *(const bf16x8*)((const char*)Qs + (w * 16 + lr) * 128 + sb);
#pragma unroll
      for (int mi = 0; mi < 4; ++mi) {
        bf16x8 kf = *(const bf16x8*)((const char*)Ks + (mi * 16 + lr) * 128 + sb);
        sacc[mi] = __builtin_amdgcn_mfma_f32_16x16x32_bf16(kf, qf, sacc[mi], 0, 0, 0);
      }
    }
    float p[4][4];
    float cmax = -INFINITY;
#pragma unroll
    for (int mi = 0; mi < 4; ++mi)
#pragma unroll
      for (int v = 0; v < 4; ++v) {
        p[mi][v] = sacc[mi][v] * 0.125f;
        cmax = fmaxf(cmax, p[mi][v]);
      }
    cmax = fmaxf(cmax, __shfl_xor(cmax, 16));
    cmax = fmaxf(cmax, __shfl_xor(cmax, 32));
    const float mnew = fmaxf(mst, cmax);
    const float al = __expf(mst - mnew);
    float csum = 0.f;
#pragma unroll
    for (int mi = 0; mi < 4; ++mi)
#pragma unroll
      for (int v = 0; v < 4; ++v) {
        p[mi][v] = __expf(p[mi][v] - mnew);
        csum += p[mi][v];
      }
    csum += __shfl_xor(csum, 16);
    csum += __shfl_xor(csum, 32);
    lst = lst * al + csum;
    mst = mnew;
#pragma unroll
    for (int mi = 0; mi < 4; ++mi) oacc[mi] *= al;
    {
      char* pbase = (char*)Ps + (w * 16 + lr) * 128;
#pragma unroll
      for (int mi = 0; mi < 4; ++mi)
#pragma unroll
        for (int vp2 = 0; vp2 < 2; ++vp2) {
          const int klo = mi * 16 + g * 4 + vp2 * 2;
          unsigned int word = (unsigned int)f2bf(p[mi][vp2 * 2]) |
                              ((unsigned int)f2bf(p[mi][vp2 * 2 + 1]) << 16);
          *(unsigned int*)(pbase + (((klo >> 3) ^ l7) << 4) + (klo & 7) * 2) = word;
        }
    }
#pragma unroll
    for (int ki = 0; ki < 2; ++ki) {
      const int sb = ((ki * 4 + g) ^ l7) << 4;
      bf16x8 pf = *(const bf16x8*)((const char*)Ps + (w * 16 + lr) * 128 + sb);
#pragma unroll
      for (int mi = 0; mi < 4; ++mi) {
        bf16x8 vf = *(const bf16x8*)((const char*)VT + (mi * 16 + lr) * 128 + sb);
        oacc[mi] = __builtin_amdgcn_mfma_f32_16x16x32_bf16(vf, pf, oacc[mi], 0, 0, 0);
      }
    }
  }
  const float inv = 1.f / lst;
  ushort_t* op = ctxb + (size_t)(b * 512 + qb * 64 + w * 16 + lr) * 512 + hh * 64;
#pragma unroll
  for (int mi = 0; mi < 4; ++mi)
#pragma unroll
    for (int vp2 = 0; vp2 < 2; ++vp2) {
      const int dh = mi * 16 + g * 4 + vp2 * 2;
      unsigned int word = (unsigned int)f2bf(oacc[mi][vp2 * 2] * inv) |
                          ((unsigned int)f2bf(oacc[mi][vp2 * 2 + 1] * inv) << 16);
      *(unsigned int*)(op + dh) = word;
    }
}

// ---------------- f32 GEMM (W_in with fused PE, fc2)
#define OUTER16(ACC, A4, B4) do { \
  ACC[0][0] += (A4).x*(B4).x; ACC[0][1] += (A4).x*(B4).y; ACC[0][2] += (A4).x*(B4).z; ACC[0][3] += (A4).x*(B4).w; \
  ACC[1][0] += (A4).y*(B4).x; ACC[1][1] += (A4).y*(B4).y; ACC[1][2] += (A4).y*(B4).z; ACC[1][3] += (A4).y*(B4).w; \
  ACC[2][0] += (A4).z*(B4).x; ACC[2][1] += (A4).z*(B4).y; ACC[2][2] += (A4).z*(B4).z; ACC[2][3] += (A4).z*(B4).w; \
  ACC[3][0] += (A4).w*(B4).x; ACC[3][1] += (A4).w*(B4).y; ACC[3][2] += (A4).w*(B4).z; ACC[3][3] += (A4).w*(B4).w; \
} while (0)

template <bool BT, bool RELU, bool PE>
__global__ __launch_bounds__(256) void gemm64(const float* __restrict__ A,
                                              const float* __restrict__ Bm,
                                              const float* __restrict__ bias,
                                              float* __restrict__ C,
                                              int M, int N, int K,
                                              const float* __restrict__ peb,
                                              ushort_t* __restrict__ hbb) {
  __shared__ float As[16][68];
  __shared__ float Bs[16][68];
  const int t = threadIdx.x;
  const int m0 = blockIdx.x << 6;
  const int n0 = blockIdx.y << 6;
  const int r0 = (t >> 4) << 2;
  const int c0 = (t & 15) << 2;
  const int lm = t >> 2;
  const int lk4 = (t & 3) << 2;
  const int lkk = t >> 4;
  const int ln = (t & 15) << 2;
  float acc[4][4] = {{0.f, 0.f, 0.f, 0.f}, {0.f, 0.f, 0.f, 0.f},
                     {0.f, 0.f, 0.f, 0.f}, {0.f, 0.f, 0.f, 0.f}};
  for (int kt = 0; kt < K; kt += 16) {
    __syncthreads();
    float4 av = *reinterpret_cast<const float4*>(A + (size_t)(m0 + lm) * K + kt + lk4);
    As[lk4 + 0][lm] = av.x; As[lk4 + 1][lm] = av.y;
    As[lk4 + 2][lm] = av.z; As[lk4 + 3][lm] = av.w;
    if (BT) {
      float4 bv = *reinterpret_cast<const float4*>(Bm + (size_t)(n0 + lm) * K + kt + lk4);
      Bs[lk4 + 0][lm] = bv.x; Bs[lk4 + 1][lm] = bv.y;
      Bs[lk4 + 2][lm] = bv.z; Bs[lk4 + 3][lm] = bv.w;
    } else {
      float4 bv = *reinterpret_cast<const float4*>(Bm + (size_t)(kt + lkk) * N + n0 + ln);
      *reinterpret_cast<float4*>(&Bs[lkk][ln]) = bv;
    }
    __syncthreads();
#pragma unroll
    for (int k = 0; k < 16; ++k) {
      float4 a4 = *reinterpret_cast<const float4*>(&As[k][r0]);
      float4 b4 = *reinterpret_cast<const float4*>(&Bs[k][c0]);
      OUTER16(acc, a4, b4);
    }
  }
  float bb0 = 0.f, bb1 = 0.f, bb2 = 0.f, bb3 = 0.f;
  if (bias) {
    bb0 = bias[n0 + c0 + 0]; bb1 = bias[n0 + c0 + 1];
    bb2 = bias[n0 + c0 + 2]; bb3 = bias[n0 + c0 + 3];
  }
#pragma unroll
  for (int i = 0; i < 4; ++i) {
    float4 o;
    o.x = acc[i][0] + bb0; o.y = acc[i][1] + bb1;
    o.z = acc[i][2] + bb2; o.w = acc[i][3] + bb3;
    if (RELU) {
      o.x = fmaxf(o.x, 0.f); o.y = fmaxf(o.y, 0.f);
      o.z = fmaxf(o.z, 0.f); o.w = fmaxf(o.w, 0.f);
    }
    const int row = m0 + r0 + i;
    if (PE) {
      float4 p = *reinterpret_cast<const float4*>(peb + (size_t)(row & 511) * 512 + n0 + c0);
      o.x += p.x; o.y += p.y; o.z += p.z; o.w += p.w;
      ushort4 ob;
      ob.x = f2bf(o.x); ob.y = f2bf(o.y); ob.z = f2bf(o.z); ob.w = f2bf(o.w);
      *reinterpret_cast<ushort4*>(hbb + (size_t)row * 512 + n0 + c0) = ob;
    }
    *reinterpret_cast<float4*>(C + (size_t)row * N + n0 + c0) = o;
  }
}

__device__ __forceinline__ float bsum256(float v, float* red) {
#pragma unroll
  for (int off = 32; off; off >>= 1) v += __shfl_down(v, off);
  __syncthreads();
  if ((threadIdx.x & 63) == 0) red[threadIdx.x >> 6] = v;
  __syncthreads();
  return red[0] + red[1] + red[2] + red[3];
}

__device__ __forceinline__ float bmax256(float v, float* red) {
#pragma unroll
  for (int off = 32; off; off >>= 1) v = fmaxf(v, __shfl_down(v, off));
  __syncthreads();
  if ((threadIdx.x & 63) == 0) red[threadIdx.x >> 6] = v;
  __syncthreads();
  return fmaxf(fmaxf(red[0], red[1]), fmaxf(red[2], red[3]));
}

// h = LN(h + res); res bf16; writes f32 h and bf16 hb (stride hbs).
__global__ __launch_bounds__(256) void ln_fused(float* __restrict__ h,
                                                ushort_t* __restrict__ hbo,
                                                int hbs,
                                                const ushort_t* __restrict__ resb,
                                                const float* __restrict__ g,
                                                const float* __restrict__ bt) {
  __shared__ float red[4];
  const size_t row = blockIdx.x;
  float* hp = h + row * 512;
  ushort_t* hbp = hbo + row * hbs;
  const ushort_t* rp = resb + row * 512;
  const int t = threadIdx.x;
  float x0 = hp[t] + bf2f(rp[t]);
  float x1 = hp[t + 256] + bf2f(rp[t + 256]);
  float mean = bsum256(x0 + x1, red) * (1.f / 512.f);
  float d0 = x0 - mean, d1 = x1 - mean;
  float var = bsum256(d0 * d0 + d1 * d1, red) * (1.f / 512.f);
  float rstd = rsqrtf(var + 1e-5f);
  float y0 = d0 * rstd * g[t] + bt[t];
  float y1 = d1 * rstd * g[t + 256] + bt[t + 256];
  hp[t] = y0; hp[t + 256] = y1;
  hbp[t] = f2bf(y0); hbp[t + 256] = f2bf(y1);
}

// softmax over 1024, writes f32 (in place) and bf16 copy.
__global__ __launch_bounds__(256) void softmax1024_cvt(float* __restrict__ p,
                                                       ushort_t* __restrict__ pb) {
  __shared__ float red[4];
  float4* rp = reinterpret_cast<float4*>(p + (size_t)blockIdx.x * 1024);
  ushort4* rb = reinterpret_cast<ushort4*>(pb + (size_t)blockIdx.x * 1024);
  const int t = threadIdx.x;
  float4 v = rp[t];
  float mx = bmax256(fmaxf(fmaxf(v.x, v.y), fmaxf(v.z, v.w)), red);
  float e0 = expf(v.x - mx), e1 = expf(v.y - mx), e2 = expf(v.z - mx), e3 = expf(v.w - mx);
  float sm = bsum256(e0 + e1 + e2 + e3, red);
  float inv = 1.f / sm;
  float4 o = make_float4(e0 * inv, e1 * inv, e2 * inv, e3 * inv);
  rp[t] = o;
  ushort4 ob;
  ob.x = f2bf(o.x); ob.y = f2bf(o.y); ob.z = f2bf(o.z); ob.w = f2bf(o.w);
  rb[t] = ob;
}

__global__ void pe_kernel(float* __restrict__ pe) {
  const int s = blockIdx.x, i = threadIdx.x;
  double div = exp((double)(2 * i) * (-log(10000.0) / 512.0));
  double a = (double)s * div;
  pe[s * 512 + 2 * i] = (float)sin(a);
  pe[s * 512 + 2 * i + 1] = (float)cos(a);
}

// One kernel for all 8 f32->bf16 weight conversions (float4 granules).
__global__ __launch_bounds__(256) void cvt_all(
    const float* __restrict__ qkvw, const float* __restrict__ outw,
    const float* __restrict__ ff1w, const float* __restrict__ ff2w,
    const float* __restrict__ memw, const float* __restrict__ fc1w,
    const float* __restrict__ gc1w, const float* __restrict__ gc2w,
    ushort_t* qkvb, ushort_t* outb, ushort_t* ff1b, ushort_t* ff2b,
    ushort_t* memb, ushort_t* fc1b, ushort_t* gc1b, ushort_t* gc2b) {
  const int gidx = blockIdx.x * 256 + threadIdx.x;  // < 2752512
  const float* s; ushort_t* d; int off;
  if (gidx < 589824)        { s = qkvw; d = qkvb; off = gidx; }
  else if (gidx < 786432)   { s = outw; d = outb; off = gidx - 589824; }
  else if (gidx < 1572864)  { s = ff1w; d = ff1b; off = gidx - 786432; }
  else if (gidx < 2359296)  { s = ff2w; d = ff2b; off = gidx - 1572864; }
  else if (gidx < 2490368)  { s = memw; d = memb; off = gidx - 2359296; }
  else if (gidx < 2621440)  { s = fc1w; d = fc1b; off = gidx - 2490368; }
  else if (gidx < 2686976)  { s = gc1w; d = gc1b; off = gidx - 2621440; }
  else                      { s = gc2w; d = gc2b; off = gidx - 2686976; }
  float4 v = reinterpret_cast<const float4*>(s)[off];
  ushort4 o;
  o.x = f2bf(v.x); o.y = f2bf(v.y); o.z = f2bf(v.z); o.w = f2bf(v.w);
  reinterpret_cast<ushort4*>(d)[off] = o;
}

// memory [1024,512] f32 -> memT bf16 [512,1024]
__global__ __launch_bounds__(256) void transpose_cvt(const float* __restrict__ in,
                                                     ushort_t* __restrict__ out) {
  const int g = blockIdx.x * 256 + threadIdx.x;
  const int r = g >> 9, c = g & 511;
  out[(size_t)c * 1024 + r] = f2bf(in[g]);
}

// x [32,512,64] f32 -> xtb [32*64, 512] bf16, LDS tiled. grid (8, 32).
__global__ __launch_bounds__(256) void transpose_x_bf16(const float* __restrict__ x,
                                                        ushort_t* __restrict__ xtb) {
  __shared__ float Ls[64][65];
  const int sc = blockIdx.x, b = blockIdx.y;
  const int t = threadIdx.x;
  const int f = t & 63, sr = t >> 6;
#pragma unroll
  for (int j = 0; j < 16; ++j) {
    const int s = sr + 4 * j;
    Ls[s][f] = x[((size_t)(b * 512 + sc * 64 + s)) * 64 + f];
  }
  __syncthreads();
#pragma unroll
  for (int j = 0; j < 16; ++j) {
    const int fr = sr * 16 + j;
    xtb[((size_t)b * 64 + fr) * 512 + sc * 64 + f] = f2bf(Ls[f][fr]);
  }
}

// fn[b] = rownorm(mean_s x[b,s,:]), 32 blocks x 256 threads, coalesced.
__global__ __launch_bounds__(256) void fmean2(const float* __restrict__ x,
                                              float* __restrict__ fn) {
  __shared__ float part[4][64];
  const int b = blockIdx.x, t = threadIdx.x;
  const int f = t & 63, sg = t >> 6;
  float acc = 0.f;
  const float* xp = x + ((size_t)b * 512 + sg) * 64 + f;
  for (int s = sg; s < 512; s += 4, xp += 256) acc += *xp;
  part[sg][f] = acc;
  __syncthreads();
  if (t < 64) {
    float m = (part[0][t] + part[1][t] + part[2][t] + part[3][t]) * (1.f / 512.f);
    float ss = m * m;
#pragma unroll
    for (int off = 32; off; off >>= 1) ss += __shfl_xor(ss, off);
    float n = fmaxf(sqrtf(ss), 1e-12f);
    fn[b * 64 + t] = m / n;
  }
}

// Parallel graph construction: 32 blocks x 256 threads (4 lanes per row).
// Exact jax.lax.top_k tie-break (lowest index on equal value).
__global__ __launch_bounds__(256) void graph_kernel2(const float* __restrict__ fn,
                                                     float* __restrict__ An) {
  __shared__ float fv[64];
  __shared__ float Am[64][65];
  const int b = blockIdx.x, t = threadIdx.x;
  const int i = t >> 2, g = t & 3;
  if (t < 64) fv[t] = fn[b * 64 + t];
#pragma unroll
  for (int j = 0; j < 16; ++j) Am[i][g * 16 + j] = 0.f;
  __syncthreads();
  const float fi = fv[i];
  unsigned int mask = 0;
  int sel[4];
  for (int r = 0; r < 4; ++r) {
    float best = -INFINITY;
    int bi = 1 << 30;
    for (int j = 0; j < 16; ++j) {
      if (mask & (1u << j)) continue;
      float v = fi * fv[g * 16 + j];
      if (v > best) { best = v; bi = g * 16 + j; }
    }
#pragma unroll
    for (int off = 1; off < 4; off <<= 1) {
      float ov = __shfl_xor(best, off);
      int oi = __shfl_xor(bi, off);
      if (ov > best || (ov == best && oi < bi)) { best = ov; bi = oi; }
    }
    sel[r] = bi;
    if ((bi >> 4) == g) mask |= 1u << (bi & 15);
  }
  if (g == 0) { Am[i][sel[1]] = 1.f; Am[i][sel[2]] = 1.f; Am[i][sel[3]] = 1.f; }
  __syncthreads();
  float vals[16];
  float deg = 0.f;
#pragma unroll
  for (int j0 = 0; j0 < 16; ++j0) {
    const int j = g * 16 + j0;
    float v = (j == i) ? 1.f : fmaxf(Am[i][j], Am[j][i]);
    vals[j0] = v;
    deg += v;
  }
#pragma unroll
  for (int off = 1; off < 4; off <<= 1) deg += __shfl_xor(deg, off);
  const float inv = 1.f / deg;
  float* out = An + ((size_t)b * 64 + i) * 64 + g * 16;
#pragma unroll
  for (int j0 = 0; j0 < 16; ++j0) out[j0] = vals[j0] * inv;
}

// Y[b] = An[b] (64x64) @ X[b] (64x512-chunk); RELU path also writes bf16 Yb.
template <bool RELU, bool STORE_T>
__global__ __launch_bounds__(256) void bmm_an(const float* __restrict__ An,
                                              const float* __restrict__ X,
                                              float* __restrict__ Y,
                                              ushort_t* __restrict__ Yb) {
  __shared__ float Ag[64][68];
  __shared__ float Xs[64][68];
  const int nc = blockIdx.x << 6;
  const int b = blockIdx.y;
  const int t = threadIdx.x;
  {
    const int i = t >> 2, g0 = (t & 3) << 4;
    const float* ap = An + ((size_t)b * 64 + i) * 64 + g0;
#pragma unroll
    for (int j = 0; j < 16; ++j) Ag[g0 + j][i] = ap[j];
  }
  {
    const int g = t >> 2, n4 = (t & 3) << 4;
    const float* xp = X + ((size_t)b * 64 + g) * 512 + nc + n4;
#pragma unroll
    for (int j = 0; j < 4; ++j)
      *reinterpret_cast<float4*>(&Xs[g][n4 + 4 * j]) =
          *reinterpret_cast<const float4*>(xp + 4 * j);
  }
  __syncthreads();
  const int r0 = (t >> 4) << 2, c0 = (t & 15) << 2;
  float acc[4][4] = {{0.f, 0.f, 0.f, 0.f}, {0.f, 0.f, 0.f, 0.f},
                     {0.f, 0.f, 0.f, 0.f}, {0.f, 0.f, 0.f, 0.f}};
#pragma unroll 8
  for (int g = 0; g < 64; ++g) {
    float4 a4 = *reinterpret_cast<const float4*>(&Ag[g][r0]);
    float4 x4 = *reinterpret_cast<const float4*>(&Xs[g][c0]);
    OUTER16(acc, a4, x4);
  }
  if (!STORE_T) {
#pragma unroll
    for (int i = 0; i < 4; ++i) {
      float4 o = make_float4(acc[i][0], acc[i][1], acc[i][2], acc[i][3]);
      if (RELU) {
        o.x = fmaxf(o.x, 0.f); o.y = fmaxf(o.y, 0.f);
        o.z = fmaxf(o.z, 0.f); o.w = fmaxf(o.w, 0.f);
      }
      *reinterpret_cast<float4*>(Y + ((size_t)b * 64 + r0 + i) * 512 + nc + c0) = o;
      if (RELU && Yb) {
        ushort4 ob;
        ob.x = f2bf(o.x); ob.y = f2bf(o.y); ob.z = f2bf(o.z); ob.w = f2bf(o.w);
        *reinterpret_cast<ushort4*>(Yb + ((size_t)b * 64 + r0 + i) * 512 + nc + c0) = ob;
      }
    }
  } else {
#pragma unroll
    for (int j = 0; j < 4; ++j) {
      float4 o = make_float4(acc[0][j], acc[1][j], acc[2][j], acc[3][j]);
      *reinterpret_cast<float4*>(Y + ((size_t)b * 512 + nc + c0 + j) * 64 + r0) = o;
    }
  }
}

}  // namespace

extern "C" void kernel_launch(void* const* d_in, const int* in_sizes, int n_in,
                              void* d_out, int out_size, void* d_ws, size_t ws_size,
                              hipStream_t stream) {
  const float* x     = (const float*)d_in[0];
  const float* W_in  = (const float*)d_in[1];
  const float* b_in  = (const float*)d_in[2];
  const float* qkv_w = (const float*)d_in[3];
  const float* qkv_b = (const float*)d_in[4];
  const float* out_w = (const float*)d_in[5];
  const float* out_b = (const float*)d_in[6];
  const float* ln1_g = (const float*)d_in[7];
  const float* ln1_b = (const float*)d_in[8];
  const float* ln2_g = (const float*)d_in[9];
  const float* ln2_b = (const float*)d_in[10];
  const float* ff1_w = (const float*)d_in[11];
  const float* ff1_b = (const float*)d_in[12];
  const float* ff2_w = (const float*)d_in[13];
  const float* ff2_b = (const float*)d_in[14];
  const float* memw  = (const float*)d_in[15];
  const float* fc1_w = (const float*)d_in[16];
  const float* fc1_b = (const float*)d_in[17];
  const float* fc2_w = (const float*)d_in[18];
  const float* fc2_b = (const float*)d_in[19];
  const float* gc1_w = (const float*)d_in[20];
  const float* gc1_b = (const float*)d_in[21];
  const float* gc2_w = (const float*)d_in[22];
  const float* gc2_b = (const float*)d_in[23];

  char* wsb = (char*)d_ws;
  float*    h      = (float*)(wsb + 0);               // 32MB
  ushort_t* hb     = (ushort_t*)(wsb + 33554432);     // 16MB
  char*     U1     = wsb + 50331648;                  // 96MB shared region
  ushort_t* ctxb   = (ushort_t*)(wsb + 150994944);    // 16MB
  ushort_t* resb   = (ushort_t*)(wsb + 167772160);    // 16MB
  float*    pe     = (float*)(wsb + 184549376);       // 1MB
  ushort_t* qkv_wb = (ushort_t*)(wsb + 185597952);    // 4.5MB
  ushort_t* out_wb = (ushort_t*)(wsb + 190316544);    // 1.5MB
  ushort_t* ff1_wb = (ushort_t*)(wsb + 191889408);    // 6MB
  ushort_t* ff2_wb = (ushort_t*)(wsb + 198180864);    // 6MB
  ushort_t* mem_b  = (ushort_t*)(wsb + 204472320);    // 1MB
  ushort_t* memT_b = (ushort_t*)(wsb + 205520896);    // 1MB
  ushort_t* fc1_wb = (ushort_t*)(wsb + 206569472);    // 1MB
  ushort_t* gc1_wb = (ushort_t*)(wsb + 207618048);    // 0.5MB
  ushort_t* gc2_wb = (ushort_t*)(wsb + 208142336);    // 0.5MB
  float*    fn     = (float*)(wsb + 208666624);       // 8KB
  float*    An     = (float*)(wsb + 208674816);       // 512KB (ends ~199.5MB)

  // U1 overlays (sequentially dead):
  ushort_t* qkvb  = (ushort_t*)U1;                     // 48MB per-layer qkv
  ushort_t* midb  = (ushort_t*)U1;                     // 64MB ff1 out
  ushort_t* attnb = (ushort_t*)U1;                     // 32MB softmax bf16
  ushort_t* catb  = (ushort_t*)(U1 + 33554432);        // 32MB [h|upd] bf16
  float*    bufC  = (float*)U1;                        // 32MB fc1 out (after upd)
  // GCN scratch (after fc2):
  ushort_t* xtb   = (ushort_t*)U1;                     // 2MB
  float*    t1    = (float*)(U1 + 2097152);            // 4MB
  float*    h1    = (float*)(U1 + 6291456);            // 4MB
  ushort_t* h1b   = (ushort_t*)(U1 + 10485760);        // 2MB
  float*    t2    = (float*)(U1 + 12582912);           // 4MB

  float* t_out = (float*)d_out;
  float* g_out = t_out + 1048576;
  float* attn  = g_out + 1048576;

  // ---- conversions / tables
  hipLaunchKernelGGL(cvt_all, dim3(10752), dim3(256), 0, stream,
                     qkv_w, out_w, ff1_w, ff2_w, memw, fc1_w, gc1_w, gc2_w,
                     qkv_wb, out_wb, ff1_wb, ff2_wb, mem_b, fc1_wb, gc1_wb, gc2_wb);
  hipLaunchKernelGGL(transpose_cvt, dim3(2048), dim3(256), 0, stream, memw, memT_b);
  hipLaunchKernelGGL(pe_kernel, dim3(512), dim3(256), 0, stream, pe);

  // ---- input projection + PE fused (writes h f32, hb bf16)
  hipLaunchKernelGGL((gemm64<true, false, true>), dim3(256, 8), dim3(256), 0, stream,
                     x, W_in, b_in, h, Mrows, 512, 64, pe, hb);

  for (int l = 0; l < 3; ++l) {
    hipLaunchKernelGGL((gemm_bf16<false, true>), dim3(128, 12), dim3(256), 0, stream,
                       hb, qkv_wb + (size_t)l * 786432, qkv_b + l * 1536, qkvb,
                       Mrows, 1536, 512, 512, 1536);
    hipLaunchKernelGGL(flash_attn_mfma, dim3(8, 8, 32), dim3(256), 0, stream, qkvb, ctxb);
    hipLaunchKernelGGL((gemm_bf16<false, true>), dim3(128, 4), dim3(256), 0, stream,
                       ctxb, out_wb + (size_t)l * 262144, out_b + l * 512, resb,
                       Mrows, 512, 512, 512, 512);
    hipLaunchKernelGGL(ln_fused, dim3(Mrows), dim3(256), 0, stream,
                       h, hb, 512, resb, ln1_g + l * 512, ln1_b + l * 512);
    hipLaunchKernelGGL((gemm_bf16<true, true>), dim3(128, 16), dim3(256), 0, stream,
                       hb, ff1_wb + (size_t)l * 1048576, ff1_b + l * 2048, midb,
                       Mrows, 2048, 512, 512, 2048);
    hipLaunchKernelGGL((gemm_bf16<false, true>), dim3(128, 4), dim3(256), 0, stream,
                       midb, ff2_wb + (size_t)l * 1048576, ff2_b + l * 512, resb,
                       Mrows, 512, 2048, 2048, 512);
    // last LN writes bf16 straight into cat layout (stride 1024)
    if (l < 2) {
      hipLaunchKernelGGL(ln_fused, dim3(Mrows), dim3(256), 0, stream,
                         h, hb, 512, resb, ln2_g + l * 512, ln2_b + l * 512);
    } else {
      hipLaunchKernelGGL(ln_fused, dim3(Mrows), dim3(256), 0, stream,
                         h, catb, 1024, resb, ln2_g + l * 512, ln2_b + l * 512);
    }
  }

  // ---- memory attention head
  hipLaunchKernelGGL((gemm_bf16<false, false>), dim3(128, 8), dim3(256), 0, stream,
                     catb, mem_b, (const float*)nullptr, attn,
                     Mrows, 1024, 512, 1024, 1024);
  hipLaunchKernelGGL(softmax1024_cvt, dim3(Mrows), dim3(256), 0, stream, attn, attnb);
  hipLaunchKernelGGL((gemm_bf16<false, true>), dim3(128, 4), dim3(256), 0, stream,
                     attnb, memT_b, (const float*)nullptr, catb + 512,
                     Mrows, 512, 1024, 1024, 1024);
  hipLaunchKernelGGL((gemm_bf16<true, false>), dim3(128, 4), dim3(256), 0, stream,
                     catb, fc1_wb, fc1_b, bufC, Mrows, 512, 1024, 1024, 512);
  hipLaunchKernelGGL((gemm64<true, false, false>), dim3(256, 1), dim3(256), 0, stream,
                     bufC, fc2_w, fc2_b, t_out, Mrows, 64, 512,
                     (const float*)nullptr, (ushort_t*)nullptr);

  // ---- GCN branch
  hipLaunchKernelGGL(fmean2, dim3(32), dim3(256), 0, stream, x, fn);
  hipLaunchKernelGGL(graph_kernel2, dim3(32), dim3(256), 0, stream, fn, An);
  hipLaunchKernelGGL(transpose_x_bf16, dim3(8, 32), dim3(256), 0, stream, x, xtb);
  hipLaunchKernelGGL((gemm_bf16<false, false>), dim3(16, 4), dim3(256), 0, stream,
                     xtb, gc1_wb, gc1_b, t1, 2048, 512, 512, 512, 512);
  hipLaunchKernelGGL((bmm_an<true, false>), dim3(8, 32), dim3(256), 0, stream,
                     An, t1, h1, h1b);
  hipLaunchKernelGGL((gemm_bf16<false, false>), dim3(16, 4), dim3(256), 0, stream,
                     h1b, gc2_wb, gc2_b, t2, 2048, 512, 512, 512, 512);
  hipLaunchKernelGGL((bmm_an<false, true>), dim3(8, 32), dim3(256), 0, stream,
                     An, t2, g_out, (ushort_t*)nullptr);
}